// Round 14
// baseline (714.992 us; speedup 1.0000x reference)
//
#include <hip/hip_runtime.h>
#include <math.h>

#define NN 50000
#define NE 800000

#define LRELU(v) fmaxf((v), 0.2f * (v))

typedef __attribute__((ext_vector_type(4))) float f32x4;
typedef __attribute__((ext_vector_type(8))) short bf16x8;

static __device__ __forceinline__ unsigned short f2bf(float f) {
  union { float f; unsigned int i; } c; c.f = f;
  unsigned int r = c.i + 0x7fff + ((c.i >> 16) & 1);   // RNE
  return (unsigned short)(r >> 16);
}
static __device__ __forceinline__ float bflo(unsigned int u) {
  union { unsigned int i; float f; } c; c.i = u << 16; return c.f;
}
static __device__ __forceinline__ float bfhi(unsigned int u) {
  union { unsigned int i; float f; } c; c.i = u & 0xffff0000u; return c.f;
}

// ---------------------------------------------------------------------------
// conv_wf: W [K][256] fp32 -> fragment-ordered bf16 table (node GEMM A-frags)
// ---------------------------------------------------------------------------
__global__ __launch_bounds__(256)
void conv_wf(const float* __restrict__ W, unsigned short* __restrict__ wf,
             int K) {
  const int g = blockIdx.x * 256 + threadIdx.x;   // K*256 total
  if (g >= K * 256) return;
  const int j = g & 7;
  const int l = (g >> 3) & 63;
  const int fn = g >> 9;
  const int n = fn & 15, ks = fn >> 4;
  const int k = ks * 32 + (l >> 4) * 8 + j;
  const int c = n * 16 + (l & 15);
  wf[g] = f2bf(W[(size_t)k * 256 + c]);
}

// ---------------------------------------------------------------------------
// conv_wef: We [64][256] -> edge-kernel fragment table (permuted mapping)
// ---------------------------------------------------------------------------
__global__ __launch_bounds__(256)
void conv_wef(const float* __restrict__ We1, unsigned short* __restrict__ wef1,
              const float* __restrict__ We2, unsigned short* __restrict__ wef2) {
  const float* We = blockIdx.y ? We2 : We1;
  unsigned short* wef = blockIdx.y ? wef2 : wef1;
  const int g = blockIdx.x * 256 + threadIdx.x;   // 16384 total
  const int j = g & 7;
  const int l = (g >> 3) & 63;
  const int t = g >> 9;
  const int n = t & 15, half = t >> 4;
  const int k = half * 32 + (l >> 4) * 8 + j;
  const int c = ((l & 15) >> 2) * 64 + n * 4 + (l & 3);
  wef[g] = f2bf(We[(size_t)k * 256 + c]);
}

// ---------------------------------------------------------------------------
// Fused MFMA node GEMM: xl = bf16(A@Wl + bl), xr = bf16(A@Wr + br).
// ---------------------------------------------------------------------------
template <int KS>   // KS = K/32
__global__ __launch_bounds__(256)
void gemm_mfma2(const float* __restrict__ A,
                const unsigned short* __restrict__ wfl,
                const float* __restrict__ bl, unsigned short* __restrict__ outl,
                const unsigned short* __restrict__ wfr,
                const float* __restrict__ br, unsigned short* __restrict__ outr) {
  const int tid = threadIdx.x;
  const int w = tid >> 6, l = tid & 63;
  const int lid = l & 15, lg = l >> 4;
  const int row  = blockIdx.x * 64 + w * 16 + lid;
  const bool rowok = row < NN;
  const int rowv = rowok ? row : NN - 1;
  const int K = KS * 32;

  bf16x8 bfr[KS];
  const float* ap = A + (size_t)rowv * K + lg * 8;
#pragma unroll
  for (int ks = 0; ks < KS; ++ks) {
    const float4 v0 = *(const float4*)(ap + ks * 32);
    const float4 v1 = *(const float4*)(ap + ks * 32 + 4);
    bf16x8 b;
    b[0]=f2bf(v0.x); b[1]=f2bf(v0.y); b[2]=f2bf(v0.z); b[3]=f2bf(v0.w);
    b[4]=f2bf(v1.x); b[5]=f2bf(v1.y); b[6]=f2bf(v1.z); b[7]=f2bf(v1.w);
    bfr[ks] = b;
  }

  f32x4 acc[16];

  // ---- pass 1: Wl ----
#pragma unroll
  for (int n = 0; n < 16; ++n) acc[n] = (f32x4){0.f, 0.f, 0.f, 0.f};
#pragma unroll
  for (int ks = 0; ks < KS; ++ks)
#pragma unroll
    for (int n = 0; n < 16; ++n) {
      const bf16x8 a = *(const bf16x8*)(wfl + ((size_t)(ks * 16 + n) * 64 + l) * 8);
      acc[n] = __builtin_amdgcn_mfma_f32_16x16x32_bf16(a, bfr[ks], acc[n], 0, 0, 0);
    }
  if (rowok) {
#pragma unroll
    for (int n = 0; n < 16; ++n) {
      const int c0 = n * 16 + lg * 4;
      const float4 bv = *(const float4*)(bl + c0);
      ushort4 o;
      o.x = f2bf(acc[n][0] + bv.x); o.y = f2bf(acc[n][1] + bv.y);
      o.z = f2bf(acc[n][2] + bv.z); o.w = f2bf(acc[n][3] + bv.w);
      *(ushort4*)(outl + (size_t)row * 256 + c0) = o;
    }
  }

  // ---- pass 2: Wr (reuse A frags) ----
#pragma unroll
  for (int n = 0; n < 16; ++n) acc[n] = (f32x4){0.f, 0.f, 0.f, 0.f};
#pragma unroll
  for (int ks = 0; ks < KS; ++ks)
#pragma unroll
    for (int n = 0; n < 16; ++n) {
      const bf16x8 a = *(const bf16x8*)(wfr + ((size_t)(ks * 16 + n) * 64 + l) * 8);
      acc[n] = __builtin_amdgcn_mfma_f32_16x16x32_bf16(a, bfr[ks], acc[n], 0, 0, 0);
    }
  if (rowok) {
#pragma unroll
    for (int n = 0; n < 16; ++n) {
      const int c0 = n * 16 + lg * 4;
      const float4 bv = *(const float4*)(br + c0);
      ushort4 o;
      o.x = f2bf(acc[n][0] + bv.x); o.y = f2bf(acc[n][1] + bv.y);
      o.z = f2bf(acc[n][2] + bv.z); o.w = f2bf(acc[n][3] + bv.w);
      *(ushort4*)(outr + (size_t)row * 256 + c0) = o;
    }
  }
}

// ---------------------------------------------------------------------------
// CSR build
// ---------------------------------------------------------------------------
__global__ __launch_bounds__(256)
void dst_hist(const int* __restrict__ dst, int* __restrict__ cnt) {
  const int e = blockIdx.x * 256 + threadIdx.x;
  if (e < NE) atomicAdd(&cnt[dst[e]], 1);
}

// 3-phase parallel exclusive scan ------------------------------------------
__global__ __launch_bounds__(1024)
void scan_bsum(const int* __restrict__ cnt, int* __restrict__ bsum, int n) {
  __shared__ int wsum[16];
  const int tid = threadIdx.x;
  const int lane = tid & 63, wid = tid >> 6;
  const int i = blockIdx.x * 1024 + tid;
  int v = (i < n) ? cnt[i] : 0;
#pragma unroll
  for (int off = 32; off >= 1; off >>= 1) v += __shfl_xor(v, off);
  if (lane == 0) wsum[wid] = v;
  __syncthreads();
  if (tid == 0) {
    int s = 0;
#pragma unroll
    for (int k = 0; k < 16; ++k) s += wsum[k];
    bsum[blockIdx.x] = s;
  }
}

__global__ __launch_bounds__(64)
void scan_bsum_scan(int* __restrict__ bsum, int* __restrict__ row_start,
                    int nb, int n) {
  const int lane = threadIdx.x;
  const int v = (lane < nb) ? bsum[lane] : 0;
  int incl = v;
#pragma unroll
  for (int off = 1; off < 64; off <<= 1) {
    const int t = __shfl_up(incl, off);
    if (lane >= off) incl += t;
  }
  if (lane < nb) bsum[lane] = incl - v;
  if (lane == 63) row_start[n] = incl;
}

__global__ __launch_bounds__(1024)
void scan_apply(int* __restrict__ cnt, const int* __restrict__ bsum,
                int* __restrict__ row_start, int n) {
  __shared__ int wsum[16];
  __shared__ int woff[16];
  const int tid = threadIdx.x;
  const int lane = tid & 63, wid = tid >> 6;
  const int i = blockIdx.x * 1024 + tid;
  const int v = (i < n) ? cnt[i] : 0;
  int incl = v;
#pragma unroll
  for (int off = 1; off < 64; off <<= 1) {
    const int t = __shfl_up(incl, off);
    if (lane >= off) incl += t;
  }
  if (lane == 63) wsum[wid] = incl;
  __syncthreads();
  if (wid == 0) {
    const int s = (lane < 16) ? wsum[lane] : 0;
    int si = s;
#pragma unroll
    for (int off = 1; off < 16; off <<= 1) {
      const int t = __shfl_up(si, off);
      if (lane >= off) si += t;
    }
    if (lane < 16) woff[lane] = si - s;
  }
  __syncthreads();
  if (i < n) {
    const int excl = bsum[blockIdx.x] + woff[wid] + incl - v;
    row_start[i] = excl;
    cnt[i] = excl;
  }
}

__global__ __launch_bounds__(256)
void bucket_fill(const int* __restrict__ src, const int* __restrict__ dst,
                 int* __restrict__ cur, int* __restrict__ eid,
                 int* __restrict__ ssrc, int* __restrict__ sdst) {
  const int e = blockIdx.x * 256 + threadIdx.x;
  if (e < NE) {
    const int d = dst[e];
    const int p = atomicAdd(&cur[d], 1);
    eid[p] = e;
    ssrc[p] = src[e];
    sdst[p] = d;
  }
}

// ---------------------------------------------------------------------------
// eab prep: eab[p][c] = bf16(ea[eid[p]][c]).
// ---------------------------------------------------------------------------
__global__ __launch_bounds__(256)
void conv_eab(const float* __restrict__ ea, const int* __restrict__ eid,
              unsigned short* __restrict__ eab) {
  const int g = blockIdx.x * 256 + threadIdx.x;
  const int p = g >> 4, c4 = (g & 15) * 4;
  const int e = eid[p];
  const float4 v = *(const float4*)(ea + (size_t)e * 64 + c4);
  ushort4 o;
  o.x = f2bf(v.x); o.y = f2bf(v.y); o.z = f2bf(v.z); o.w = f2bf(v.w);
  *(ushort4*)(eab + (size_t)p * 64 + c4) = o;
}

// ---------------------------------------------------------------------------
// Edge kernel: swapped-operand MFMA, permuted col mapping (lane-local logit),
// wave-private LDS xl staging, 128-thread blocks.
// ---------------------------------------------------------------------------
template <int EAB>
__global__ __launch_bounds__(128)
void edge_logits_swap(const float* __restrict__ ea,
                      const unsigned short* __restrict__ eab,
                      const unsigned short* __restrict__ wef,  // [2][16][64][8]
                      const unsigned short* __restrict__ xlb,
                      const unsigned short* __restrict__ xrb,
                      const float* __restrict__ att,
                      const int* __restrict__ eid,
                      const int* __restrict__ ssrc, const int* __restrict__ sdst,
                      float* __restrict__ elog) {
  __shared__ unsigned short sxl[2][16 * 264];   // 2 x 8448 B

  const int tid = threadIdx.x;
  const int w = tid >> 6, l = tid & 63;
  const int lid = l & 15, lg = l >> 4;
  const int p0 = (blockIdx.x * 2 + w) * 16;
  const int p  = p0 + lid;

  // B-frags first (independent of ssrc)
  bf16x8 f0, f1;
  if (EAB) {
    f0 = *(const bf16x8*)(eab + (size_t)p * 64 + lg * 8);
    f1 = *(const bf16x8*)(eab + (size_t)p * 64 + 32 + lg * 8);
  } else {
    const int e = eid[p];
    const float* ap = ea + (size_t)e * 64 + lg * 8;
    const float4 v00 = *(const float4*)(ap);
    const float4 v01 = *(const float4*)(ap + 4);
    const float4 v10 = *(const float4*)(ap + 32);
    const float4 v11 = *(const float4*)(ap + 36);
    f0[0]=f2bf(v00.x); f0[1]=f2bf(v00.y); f0[2]=f2bf(v00.z); f0[3]=f2bf(v00.w);
    f0[4]=f2bf(v01.x); f0[5]=f2bf(v01.y); f0[6]=f2bf(v01.z); f0[7]=f2bf(v01.w);
    f1[0]=f2bf(v10.x); f1[1]=f2bf(v10.y); f1[2]=f2bf(v10.z); f1[3]=f2bf(v10.w);
    f1[4]=f2bf(v11.x); f1[5]=f2bf(v11.y); f1[6]=f2bf(v11.z); f1[7]=f2bf(v11.w);
  }

  const int d = sdst[p];
  unsigned short* myxl = sxl[w];

  // cooperative stage: instr i loads rows {2i, 2i+1}
#pragma unroll
  for (int i = 0; i < 8; ++i) {
    const int row  = i * 2 + (l >> 5);
    const int unit = l & 31;
    const int srow = ssrc[p0 + row];
    const uint4 v = *(const uint4*)(xlb + (size_t)srow * 256 + unit * 8);
    *(uint4*)&myxl[row * 264 + unit * 8] = v;
  }

  const unsigned short* xlp  = myxl + lid * 264 + lg * 64;   // LDS
  const unsigned short* xrp  = xrb + (size_t)d * 256 + lg * 64;
  const float* attp = att + lg * 64;

  float ph = 0.f;
#pragma unroll
  for (int nn = 0; nn < 8; ++nn) {
    const bf16x8 w00 = *(const bf16x8*)(wef + ((size_t)(0  + 2 * nn)     * 64 + l) * 8);
    const bf16x8 w01 = *(const bf16x8*)(wef + ((size_t)(16 + 2 * nn)     * 64 + l) * 8);
    const bf16x8 w10 = *(const bf16x8*)(wef + ((size_t)(0  + 2 * nn + 1) * 64 + l) * 8);
    const bf16x8 w11 = *(const bf16x8*)(wef + ((size_t)(16 + 2 * nn + 1) * 64 + l) * 8);

    f32x4 a0 = (f32x4){0.f,0.f,0.f,0.f}, a1 = (f32x4){0.f,0.f,0.f,0.f};
    a0 = __builtin_amdgcn_mfma_f32_16x16x32_bf16(w00, f0, a0, 0, 0, 0);
    a0 = __builtin_amdgcn_mfma_f32_16x16x32_bf16(w01, f1, a0, 0, 0, 0);
    a1 = __builtin_amdgcn_mfma_f32_16x16x32_bf16(w10, f0, a1, 0, 0, 0);
    a1 = __builtin_amdgcn_mfma_f32_16x16x32_bf16(w11, f1, a1, 0, 0, 0);

    const int c0 = nn * 8;
    const uint4 xu = *(const uint4*)(xlp + c0);
    const uint4 ru = *(const uint4*)(xrp + c0);
    const float4 at0 = *(const float4*)(attp + c0);
    const float4 at1 = *(const float4*)(attp + c0 + 4);
    float v;
    v = a0[0] + bflo(xu.x) + bflo(ru.x); v = LRELU(v); ph += v * at0.x;
    v = a0[1] + bfhi(xu.x) + bfhi(ru.x); v = LRELU(v); ph += v * at0.y;
    v = a0[2] + bflo(xu.y) + bflo(ru.y); v = LRELU(v); ph += v * at0.z;
    v = a0[3] + bfhi(xu.y) + bfhi(ru.y); v = LRELU(v); ph += v * at0.w;
    v = a1[0] + bflo(xu.z) + bflo(ru.z); v = LRELU(v); ph += v * at1.x;
    v = a1[1] + bfhi(xu.z) + bfhi(ru.z); v = LRELU(v); ph += v * at1.y;
    v = a1[2] + bflo(xu.w) + bflo(ru.w); v = LRELU(v); ph += v * at1.z;
    v = a1[3] + bfhi(xu.w) + bfhi(ru.w); v = LRELU(v); ph += v * at1.w;
  }

  elog[(size_t)p * 4 + lg] = expf(ph);
}

// ---------------------------------------------------------------------------
// Aggregation (coalesced): one wave per dst node, 4 nodes/block.
// lane -> (row parity l>>5, col group l&31): one gather instr covers TWO
// full xlb rows (64 lanes x 16B = 8 cache lines, the minimum). 8 fp32
// accumulators/lane; shfl_xor(32) merges parities; 32-lane coalesced write.
// ---------------------------------------------------------------------------
__global__ __launch_bounds__(256)
void aggregate(const unsigned short* __restrict__ xlb,
               const float* __restrict__ elog,
               const int* __restrict__ ssrc, const int* __restrict__ row_start,
               const float* __restrict__ bias, float* __restrict__ out) {
  const int wid = threadIdx.x >> 6;
  const int l   = threadIdx.x & 63;
  const int d   = blockIdx.x * 4 + wid;
  const int rp  = l >> 5;          // row parity
  const int cg  = l & 31;          // col group -> cols cg*8..cg*8+7
  const int c8  = cg * 8;
  const int h   = cg >> 3;         // head of my col range
  const int beg = row_start[d], end = row_start[d + 1];

  float a0=0.f,a1=0.f,a2=0.f,a3=0.f,a4=0.f,a5=0.f,a6=0.f,a7=0.f;
  float dtot = 0.f;

  for (int pb = beg; pb < end; pb += 2) {
    const int p = pb + rp;
    const bool valid = p < end;
    const int s = ssrc[valid ? p : beg];
    const uint4 xv = *(const uint4*)(xlb + (size_t)s * 256 + c8);
    const float ev = valid ? elog[(size_t)p * 4 + h] : 0.f;
    a0 += ev * bflo(xv.x); a1 += ev * bfhi(xv.x);
    a2 += ev * bflo(xv.y); a3 += ev * bfhi(xv.y);
    a4 += ev * bflo(xv.z); a5 += ev * bfhi(xv.z);
    a6 += ev * bflo(xv.w); a7 += ev * bfhi(xv.w);
    dtot += ev;
  }

  a0 += __shfl_xor(a0, 32); a1 += __shfl_xor(a1, 32);
  a2 += __shfl_xor(a2, 32); a3 += __shfl_xor(a3, 32);
  a4 += __shfl_xor(a4, 32); a5 += __shfl_xor(a5, 32);
  a6 += __shfl_xor(a6, 32); a7 += __shfl_xor(a7, 32);
  dtot += __shfl_xor(dtot, 32);

  if (rp == 0) {
    const float inv = 1.f / (dtot + 1e-16f);
    const float4 b0 = *(const float4*)(bias + c8);
    const float4 b1 = *(const float4*)(bias + c8 + 4);
    float4 o0, o1;
    o0.x = b0.x + a0 * inv; o0.y = b0.y + a1 * inv;
    o0.z = b0.z + a2 * inv; o0.w = b0.w + a3 * inv;
    o1.x = b1.x + a4 * inv; o1.y = b1.y + a5 * inv;
    o1.z = b1.z + a6 * inv; o1.w = b1.w + a7 * inv;
    *(float4*)(out + (size_t)d * 256 + c8) = o0;
    *(float4*)(out + (size_t)d * 256 + c8 + 4) = o1;
  }
}

extern "C" void kernel_launch(void* const* d_in, const int* in_sizes, int n_in,
                              void* d_out, int out_size, void* d_ws, size_t ws_size,
                              hipStream_t stream) {
  const float* x    = (const float*)d_in[0];
  const int*   ei   = (const int*)d_in[1];
  const float* ea   = (const float*)d_in[2];
  const float* Wl1  = (const float*)d_in[3];
  const float* bl1  = (const float*)d_in[4];
  const float* Wr1  = (const float*)d_in[5];
  const float* br1  = (const float*)d_in[6];
  const float* We1  = (const float*)d_in[7];
  const float* att1 = (const float*)d_in[8];
  const float* bias1= (const float*)d_in[9];
  const float* Wl2  = (const float*)d_in[10];
  const float* bl2  = (const float*)d_in[11];
  const float* Wr2  = (const float*)d_in[12];
  const float* br2  = (const float*)d_in[13];
  const float* We2  = (const float*)d_in[14];
  const float* att2 = (const float*)d_in[15];
  const float* bias2= (const float*)d_in[16];

  float* out = (float*)d_out;
  float* ws  = (float*)d_ws;

  float* elog = ws;                                    // NE*4 f32
  unsigned short* xlb  = (unsigned short*)(elog + (size_t)NE * 4); // NN*256
  unsigned short* xrb  = xlb + (size_t)NN * 256;       // NN*256
  unsigned short* wef1 = xrb + (size_t)NN * 256;       // 16384
  unsigned short* wef2 = wef1 + 16384;                 // 16384
  unsigned short* wlf1 = wef2 + 16384;                 // 32768
  unsigned short* wrf1 = wlf1 + 32768;                 // 32768
  unsigned short* wlf2 = wrf1 + 32768;                 // 65536
  unsigned short* wrf2 = wlf2 + 65536;                 // 65536
  int* cur       = (int*)(wrf2 + 65536);               // NN
  int* row_start = cur + NN;                           // NN+1
  int* bsum      = row_start + NN + 1;                 // 64
  int* eid       = bsum + 64;                          // NE
  int* ssrc      = eid + NE;                           // NE
  int* sdst      = ssrc + NE;                          // NE
  unsigned short* eab = (unsigned short*)(sdst + NE);  // NE*64 bf16 (optional)
  const size_t need_eab =
      ((char*)(eab + (size_t)NE * 64)) - (char*)d_ws;
  const bool use_eab = ws_size >= need_eab;
  float* h1 = out;  // d_out doubles as h1

  const int* src = ei;
  const int* dst = ei + NE;

  const int ggrid = (NN + 63) / 64;      // 782
  const int egrid = NE / 32;             // 25000
  const int epb   = (NE + 255) / 256;
  const int agrid = NN / 4;              // 12500
  const int nb    = (NN + 1023) / 1024;  // 49

  // ---- prep: CSR + bf16 weight tables (+ eab) ----
  hipMemsetAsync(cur, 0, NN * sizeof(int), stream);
  conv_wef<<<dim3(64, 2), 256, 0, stream>>>(We1, wef1, We2, wef2);
  conv_wf<<<128, 256, 0, stream>>>(Wl1, wlf1, 128);
  conv_wf<<<128, 256, 0, stream>>>(Wr1, wrf1, 128);
  conv_wf<<<256, 256, 0, stream>>>(Wl2, wlf2, 256);
  conv_wf<<<256, 256, 0, stream>>>(Wr2, wrf2, 256);
  dst_hist<<<epb, 256, 0, stream>>>(dst, cur);
  scan_bsum<<<nb, 1024, 0, stream>>>(cur, bsum, NN);
  scan_bsum_scan<<<1, 64, 0, stream>>>(bsum, row_start, nb, NN);
  scan_apply<<<nb, 1024, 0, stream>>>(cur, bsum, row_start, NN);
  bucket_fill<<<epb, 256, 0, stream>>>(src, dst, cur, eid, ssrc, sdst);
  if (use_eab)
    conv_eab<<<NE * 16 / 256, 256, 0, stream>>>(ea, eid, eab);

  // ---- layer 1 ----
  gemm_mfma2<4><<<ggrid, 256, 0, stream>>>(x, wlf1, bl1, xlb, wrf1, br1, xrb);
  if (use_eab)
    edge_logits_swap<1><<<egrid, 128, 0, stream>>>(ea, eab, wef1, xlb, xrb,
                                                   att1, eid, ssrc, sdst, elog);
  else
    edge_logits_swap<0><<<egrid, 128, 0, stream>>>(ea, eab, wef1, xlb, xrb,
                                                   att1, eid, ssrc, sdst, elog);
  aggregate<<<agrid, 256, 0, stream>>>(xlb, elog, ssrc, row_start, bias1, h1);

  // ---- layer 2 ----
  gemm_mfma2<8><<<ggrid, 256, 0, stream>>>(h1, wlf2, bl2, xlb, wrf2, br2, xrb);
  if (use_eab)
    edge_logits_swap<1><<<egrid, 128, 0, stream>>>(ea, eab, wef2, xlb, xrb,
                                                   att2, eid, ssrc, sdst, elog);
  else
    edge_logits_swap<0><<<egrid, 128, 0, stream>>>(ea, eab, wef2, xlb, xrb,
                                                   att2, eid, ssrc, sdst, elog);
  aggregate<<<agrid, 256, 0, stream>>>(xlb, elog, ssrc, row_start, bias2, out);
}

// Round 15
// 693.492 us; speedup vs baseline: 1.0310x; 1.0310x over previous
//
#include <hip/hip_runtime.h>
#include <math.h>

#define NN 50000
#define NE 800000

#define LRELU(v) fmaxf((v), 0.2f * (v))

typedef __attribute__((ext_vector_type(4))) float f32x4;
typedef __attribute__((ext_vector_type(8))) short bf16x8;

static __device__ __forceinline__ unsigned short f2bf(float f) {
  union { float f; unsigned int i; } c; c.f = f;
  unsigned int r = c.i + 0x7fff + ((c.i >> 16) & 1);   // RNE
  return (unsigned short)(r >> 16);
}
static __device__ __forceinline__ float bflo(unsigned int u) {
  union { unsigned int i; float f; } c; c.i = u << 16; return c.f;
}
static __device__ __forceinline__ float bfhi(unsigned int u) {
  union { unsigned int i; float f; } c; c.i = u & 0xffff0000u; return c.f;
}

// ---------------------------------------------------------------------------
// conv_all: all 6 bf16 weight tables in ONE dispatch. blockIdx.y:
//   0: We1->wef1, 1: We2->wef2 (edge permuted frag order, 16384 elems)
//   2: Wl1->wlf1, 3: Wr1->wrf1 (K=128, 32768 elems)
//   4: Wl2->wlf2, 5: Wr2->wrf2 (K=256, 65536 elems)
// ---------------------------------------------------------------------------
__global__ __launch_bounds__(256)
void conv_all(const float* __restrict__ We1, unsigned short* __restrict__ wef1,
              const float* __restrict__ We2, unsigned short* __restrict__ wef2,
              const float* __restrict__ Wl1, unsigned short* __restrict__ wlf1,
              const float* __restrict__ Wr1, unsigned short* __restrict__ wrf1,
              const float* __restrict__ Wl2, unsigned short* __restrict__ wlf2,
              const float* __restrict__ Wr2, unsigned short* __restrict__ wrf2) {
  const int y = blockIdx.y;
  const int g = blockIdx.x * 256 + threadIdx.x;
  if (y < 2) {
    if (g >= 16384) return;
    const float* We = y ? We2 : We1;
    unsigned short* wef = y ? wef2 : wef1;
    const int j = g & 7;
    const int l = (g >> 3) & 63;
    const int t = g >> 9;
    const int n = t & 15, half = t >> 4;
    const int k = half * 32 + (l >> 4) * 8 + j;
    const int c = ((l & 15) >> 2) * 64 + n * 4 + (l & 3);
    wef[g] = f2bf(We[(size_t)k * 256 + c]);
  } else {
    const int K = (y < 4) ? 128 : 256;
    if (g >= K * 256) return;
    const float* W = (y == 2) ? Wl1 : (y == 3) ? Wr1 : (y == 4) ? Wl2 : Wr2;
    unsigned short* wf = (y == 2) ? wlf1 : (y == 3) ? wrf1
                       : (y == 4) ? wlf2 : wrf2;
    const int j = g & 7;
    const int l = (g >> 3) & 63;
    const int fn = g >> 9;
    const int n = fn & 15, ks = fn >> 4;
    const int k = ks * 32 + (l >> 4) * 8 + j;
    const int c = n * 16 + (l & 15);
    wf[g] = f2bf(W[(size_t)k * 256 + c]);
  }
}

// ---------------------------------------------------------------------------
// Fused MFMA node GEMM: xl = bf16(A@Wl + bl), xr = bf16(A@Wr + br).
// ---------------------------------------------------------------------------
template <int KS>   // KS = K/32
__global__ __launch_bounds__(256)
void gemm_mfma2(const float* __restrict__ A,
                const unsigned short* __restrict__ wfl,
                const float* __restrict__ bl, unsigned short* __restrict__ outl,
                const unsigned short* __restrict__ wfr,
                const float* __restrict__ br, unsigned short* __restrict__ outr) {
  const int tid = threadIdx.x;
  const int w = tid >> 6, l = tid & 63;
  const int lid = l & 15, lg = l >> 4;
  const int row  = blockIdx.x * 64 + w * 16 + lid;
  const bool rowok = row < NN;
  const int rowv = rowok ? row : NN - 1;
  const int K = KS * 32;

  bf16x8 bfr[KS];
  const float* ap = A + (size_t)rowv * K + lg * 8;
#pragma unroll
  for (int ks = 0; ks < KS; ++ks) {
    const float4 v0 = *(const float4*)(ap + ks * 32);
    const float4 v1 = *(const float4*)(ap + ks * 32 + 4);
    bf16x8 b;
    b[0]=f2bf(v0.x); b[1]=f2bf(v0.y); b[2]=f2bf(v0.z); b[3]=f2bf(v0.w);
    b[4]=f2bf(v1.x); b[5]=f2bf(v1.y); b[6]=f2bf(v1.z); b[7]=f2bf(v1.w);
    bfr[ks] = b;
  }

  f32x4 acc[16];

  // ---- pass 1: Wl ----
#pragma unroll
  for (int n = 0; n < 16; ++n) acc[n] = (f32x4){0.f, 0.f, 0.f, 0.f};
#pragma unroll
  for (int ks = 0; ks < KS; ++ks)
#pragma unroll
    for (int n = 0; n < 16; ++n) {
      const bf16x8 a = *(const bf16x8*)(wfl + ((size_t)(ks * 16 + n) * 64 + l) * 8);
      acc[n] = __builtin_amdgcn_mfma_f32_16x16x32_bf16(a, bfr[ks], acc[n], 0, 0, 0);
    }
  if (rowok) {
#pragma unroll
    for (int n = 0; n < 16; ++n) {
      const int c0 = n * 16 + lg * 4;
      const float4 bv = *(const float4*)(bl + c0);
      ushort4 o;
      o.x = f2bf(acc[n][0] + bv.x); o.y = f2bf(acc[n][1] + bv.y);
      o.z = f2bf(acc[n][2] + bv.z); o.w = f2bf(acc[n][3] + bv.w);
      *(ushort4*)(outl + (size_t)row * 256 + c0) = o;
    }
  }

  // ---- pass 2: Wr (reuse A frags) ----
#pragma unroll
  for (int n = 0; n < 16; ++n) acc[n] = (f32x4){0.f, 0.f, 0.f, 0.f};
#pragma unroll
  for (int ks = 0; ks < KS; ++ks)
#pragma unroll
    for (int n = 0; n < 16; ++n) {
      const bf16x8 a = *(const bf16x8*)(wfr + ((size_t)(ks * 16 + n) * 64 + l) * 8);
      acc[n] = __builtin_amdgcn_mfma_f32_16x16x32_bf16(a, bfr[ks], acc[n], 0, 0, 0);
    }
  if (rowok) {
#pragma unroll
    for (int n = 0; n < 16; ++n) {
      const int c0 = n * 16 + lg * 4;
      const float4 bv = *(const float4*)(br + c0);
      ushort4 o;
      o.x = f2bf(acc[n][0] + bv.x); o.y = f2bf(acc[n][1] + bv.y);
      o.z = f2bf(acc[n][2] + bv.z); o.w = f2bf(acc[n][3] + bv.w);
      *(ushort4*)(outr + (size_t)row * 256 + c0) = o;
    }
  }
}

// ---------------------------------------------------------------------------
// CSR build
// ---------------------------------------------------------------------------
__global__ __launch_bounds__(256)
void dst_hist(const int* __restrict__ dst, int* __restrict__ cnt) {
  const int e = blockIdx.x * 256 + threadIdx.x;
  if (e < NE) atomicAdd(&cnt[dst[e]], 1);
}

// 3-phase parallel exclusive scan ------------------------------------------
__global__ __launch_bounds__(1024)
void scan_bsum(const int* __restrict__ cnt, int* __restrict__ bsum, int n) {
  __shared__ int wsum[16];
  const int tid = threadIdx.x;
  const int lane = tid & 63, wid = tid >> 6;
  const int i = blockIdx.x * 1024 + tid;
  int v = (i < n) ? cnt[i] : 0;
#pragma unroll
  for (int off = 32; off >= 1; off >>= 1) v += __shfl_xor(v, off);
  if (lane == 0) wsum[wid] = v;
  __syncthreads();
  if (tid == 0) {
    int s = 0;
#pragma unroll
    for (int k = 0; k < 16; ++k) s += wsum[k];
    bsum[blockIdx.x] = s;
  }
}

__global__ __launch_bounds__(64)
void scan_bsum_scan(int* __restrict__ bsum, int* __restrict__ row_start,
                    int nb, int n) {
  const int lane = threadIdx.x;
  const int v = (lane < nb) ? bsum[lane] : 0;
  int incl = v;
#pragma unroll
  for (int off = 1; off < 64; off <<= 1) {
    const int t = __shfl_up(incl, off);
    if (lane >= off) incl += t;
  }
  if (lane < nb) bsum[lane] = incl - v;
  if (lane == 63) row_start[n] = incl;
}

__global__ __launch_bounds__(1024)
void scan_apply(int* __restrict__ cnt, const int* __restrict__ bsum,
                int* __restrict__ row_start, int n) {
  __shared__ int wsum[16];
  __shared__ int woff[16];
  const int tid = threadIdx.x;
  const int lane = tid & 63, wid = tid >> 6;
  const int i = blockIdx.x * 1024 + tid;
  const int v = (i < n) ? cnt[i] : 0;
  int incl = v;
#pragma unroll
  for (int off = 1; off < 64; off <<= 1) {
    const int t = __shfl_up(incl, off);
    if (lane >= off) incl += t;
  }
  if (lane == 63) wsum[wid] = incl;
  __syncthreads();
  if (wid == 0) {
    const int s = (lane < 16) ? wsum[lane] : 0;
    int si = s;
#pragma unroll
    for (int off = 1; off < 16; off <<= 1) {
      const int t = __shfl_up(si, off);
      if (lane >= off) si += t;
    }
    if (lane < 16) woff[lane] = si - s;
  }
  __syncthreads();
  if (i < n) {
    const int excl = bsum[blockIdx.x] + woff[wid] + incl - v;
    row_start[i] = excl;
    cnt[i] = excl;
  }
}

__global__ __launch_bounds__(256)
void bucket_fill(const int* __restrict__ src, const int* __restrict__ dst,
                 int* __restrict__ cur, int* __restrict__ eid,
                 int* __restrict__ ssrc, int* __restrict__ sdst) {
  const int e = blockIdx.x * 256 + threadIdx.x;
  if (e < NE) {
    const int d = dst[e];
    const int p = atomicAdd(&cur[d], 1);
    eid[p] = e;
    ssrc[p] = src[e];
    sdst[p] = d;
  }
}

// ---------------------------------------------------------------------------
// eab prep: eab[p][c] = bf16(ea[eid[p]][c]).
// ---------------------------------------------------------------------------
__global__ __launch_bounds__(256)
void conv_eab(const float* __restrict__ ea, const int* __restrict__ eid,
              unsigned short* __restrict__ eab) {
  const int g = blockIdx.x * 256 + threadIdx.x;
  const int p = g >> 4, c4 = (g & 15) * 4;
  const int e = eid[p];
  const float4 v = *(const float4*)(ea + (size_t)e * 64 + c4);
  ushort4 o;
  o.x = f2bf(v.x); o.y = f2bf(v.y); o.z = f2bf(v.z); o.w = f2bf(v.w);
  *(ushort4*)(eab + (size_t)p * 64 + c4) = o;
}

// ---------------------------------------------------------------------------
// Edge kernel: swapped-operand MFMA, permuted col mapping (lane-local logit),
// wave-private LDS xl staging, 128-thread blocks. (R14 version, 131 us)
// ---------------------------------------------------------------------------
template <int EAB>
__global__ __launch_bounds__(128)
void edge_logits_swap(const float* __restrict__ ea,
                      const unsigned short* __restrict__ eab,
                      const unsigned short* __restrict__ wef,  // [2][16][64][8]
                      const unsigned short* __restrict__ xlb,
                      const unsigned short* __restrict__ xrb,
                      const float* __restrict__ att,
                      const int* __restrict__ eid,
                      const int* __restrict__ ssrc, const int* __restrict__ sdst,
                      float* __restrict__ elog) {
  __shared__ unsigned short sxl[2][16 * 264];   // 2 x 8448 B

  const int tid = threadIdx.x;
  const int w = tid >> 6, l = tid & 63;
  const int lid = l & 15, lg = l >> 4;
  const int p0 = (blockIdx.x * 2 + w) * 16;
  const int p  = p0 + lid;

  // B-frags first (independent of ssrc)
  bf16x8 f0, f1;
  if (EAB) {
    f0 = *(const bf16x8*)(eab + (size_t)p * 64 + lg * 8);
    f1 = *(const bf16x8*)(eab + (size_t)p * 64 + 32 + lg * 8);
  } else {
    const int e = eid[p];
    const float* ap = ea + (size_t)e * 64 + lg * 8;
    const float4 v00 = *(const float4*)(ap);
    const float4 v01 = *(const float4*)(ap + 4);
    const float4 v10 = *(const float4*)(ap + 32);
    const float4 v11 = *(const float4*)(ap + 36);
    f0[0]=f2bf(v00.x); f0[1]=f2bf(v00.y); f0[2]=f2bf(v00.z); f0[3]=f2bf(v00.w);
    f0[4]=f2bf(v01.x); f0[5]=f2bf(v01.y); f0[6]=f2bf(v01.z); f0[7]=f2bf(v01.w);
    f1[0]=f2bf(v10.x); f1[1]=f2bf(v10.y); f1[2]=f2bf(v10.z); f1[3]=f2bf(v10.w);
    f1[4]=f2bf(v11.x); f1[5]=f2bf(v11.y); f1[6]=f2bf(v11.z); f1[7]=f2bf(v11.w);
  }

  const int d = sdst[p];
  unsigned short* myxl = sxl[w];

  // cooperative stage: instr i loads rows {2i, 2i+1}
#pragma unroll
  for (int i = 0; i < 8; ++i) {
    const int row  = i * 2 + (l >> 5);
    const int unit = l & 31;
    const int srow = ssrc[p0 + row];
    const uint4 v = *(const uint4*)(xlb + (size_t)srow * 256 + unit * 8);
    *(uint4*)&myxl[row * 264 + unit * 8] = v;
  }

  const unsigned short* xlp  = myxl + lid * 264 + lg * 64;   // LDS
  const unsigned short* xrp  = xrb + (size_t)d * 256 + lg * 64;
  const float* attp = att + lg * 64;

  float ph = 0.f;
#pragma unroll
  for (int nn = 0; nn < 8; ++nn) {
    const bf16x8 w00 = *(const bf16x8*)(wef + ((size_t)(0  + 2 * nn)     * 64 + l) * 8);
    const bf16x8 w01 = *(const bf16x8*)(wef + ((size_t)(16 + 2 * nn)     * 64 + l) * 8);
    const bf16x8 w10 = *(const bf16x8*)(wef + ((size_t)(0  + 2 * nn + 1) * 64 + l) * 8);
    const bf16x8 w11 = *(const bf16x8*)(wef + ((size_t)(16 + 2 * nn + 1) * 64 + l) * 8);

    f32x4 a0 = (f32x4){0.f,0.f,0.f,0.f}, a1 = (f32x4){0.f,0.f,0.f,0.f};
    a0 = __builtin_amdgcn_mfma_f32_16x16x32_bf16(w00, f0, a0, 0, 0, 0);
    a0 = __builtin_amdgcn_mfma_f32_16x16x32_bf16(w01, f1, a0, 0, 0, 0);
    a1 = __builtin_amdgcn_mfma_f32_16x16x32_bf16(w10, f0, a1, 0, 0, 0);
    a1 = __builtin_amdgcn_mfma_f32_16x16x32_bf16(w11, f1, a1, 0, 0, 0);

    const int c0 = nn * 8;
    const uint4 xu = *(const uint4*)(xlp + c0);
    const uint4 ru = *(const uint4*)(xrp + c0);
    const float4 at0 = *(const float4*)(attp + c0);
    const float4 at1 = *(const float4*)(attp + c0 + 4);
    float v;
    v = a0[0] + bflo(xu.x) + bflo(ru.x); v = LRELU(v); ph += v * at0.x;
    v = a0[1] + bfhi(xu.x) + bfhi(ru.x); v = LRELU(v); ph += v * at0.y;
    v = a0[2] + bflo(xu.y) + bflo(ru.y); v = LRELU(v); ph += v * at0.z;
    v = a0[3] + bfhi(xu.y) + bfhi(ru.y); v = LRELU(v); ph += v * at0.w;
    v = a1[0] + bflo(xu.z) + bflo(ru.z); v = LRELU(v); ph += v * at1.x;
    v = a1[1] + bfhi(xu.z) + bfhi(ru.z); v = LRELU(v); ph += v * at1.y;
    v = a1[2] + bflo(xu.w) + bflo(ru.w); v = LRELU(v); ph += v * at1.z;
    v = a1[3] + bfhi(xu.w) + bfhi(ru.w); v = LRELU(v); ph += v * at1.w;
  }

  elog[(size_t)p * 4 + lg] = expf(ph);
}

// ---------------------------------------------------------------------------
// Aggregation (R13 known-good): one wave per dst node, 4 nodes/block;
// 4-deep unrolled independent loads.
// ---------------------------------------------------------------------------
__global__ __launch_bounds__(256)
void aggregate(const unsigned short* __restrict__ xlb,
               const float* __restrict__ elog,
               const int* __restrict__ ssrc, const int* __restrict__ row_start,
               const float* __restrict__ bias, float* __restrict__ out) {
  const int wid  = threadIdx.x >> 6;
  const int lane = threadIdx.x & 63;
  const int d    = blockIdx.x * 4 + wid;
  const int h = lane >> 4;
  const int c = lane * 4;
  float ax = 0.f, ay = 0.f, az = 0.f, aw = 0.f;
  float dtot = 0.f;
  const int beg = row_start[d], end = row_start[d + 1];
  int p = beg;
  for (; p + 4 <= end; p += 4) {
    const float e0 = elog[(size_t)(p + 0) * 4 + h];
    const float e1 = elog[(size_t)(p + 1) * 4 + h];
    const float e2 = elog[(size_t)(p + 2) * 4 + h];
    const float e3 = elog[(size_t)(p + 3) * 4 + h];
    const int s0 = ssrc[p + 0], s1 = ssrc[p + 1];
    const int s2 = ssrc[p + 2], s3 = ssrc[p + 3];
    const uint2 x0 = *(const uint2*)(xlb + (size_t)s0 * 256 + c);
    const uint2 x1 = *(const uint2*)(xlb + (size_t)s1 * 256 + c);
    const uint2 x2 = *(const uint2*)(xlb + (size_t)s2 * 256 + c);
    const uint2 x3 = *(const uint2*)(xlb + (size_t)s3 * 256 + c);
    ax += e0*bflo(x0.x) + e1*bflo(x1.x) + e2*bflo(x2.x) + e3*bflo(x3.x);
    ay += e0*bfhi(x0.x) + e1*bfhi(x1.x) + e2*bfhi(x2.x) + e3*bfhi(x3.x);
    az += e0*bflo(x0.y) + e1*bflo(x1.y) + e2*bflo(x2.y) + e3*bflo(x3.y);
    aw += e0*bfhi(x0.y) + e1*bfhi(x1.y) + e2*bfhi(x2.y) + e3*bfhi(x3.y);
    dtot += e0 + e1 + e2 + e3;
  }
  for (; p < end; ++p) {
    const float ev = elog[(size_t)p * 4 + h];
    const int s = ssrc[p];
    const uint2 xv = *(const uint2*)(xlb + (size_t)s * 256 + c);
    ax += ev * bflo(xv.x); ay += ev * bfhi(xv.x);
    az += ev * bflo(xv.y); aw += ev * bfhi(xv.y);
    dtot += ev;
  }
  const float inv = 1.f / (dtot + 1e-16f);
  const float4 bv = *(const float4*)(bias + c);
  float4 o;
  o.x = bv.x + ax * inv; o.y = bv.y + ay * inv;
  o.z = bv.z + az * inv; o.w = bv.w + aw * inv;
  *(float4*)(out + (size_t)d * 256 + c) = o;
}

extern "C" void kernel_launch(void* const* d_in, const int* in_sizes, int n_in,
                              void* d_out, int out_size, void* d_ws, size_t ws_size,
                              hipStream_t stream) {
  const float* x    = (const float*)d_in[0];
  const int*   ei   = (const int*)d_in[1];
  const float* ea   = (const float*)d_in[2];
  const float* Wl1  = (const float*)d_in[3];
  const float* bl1  = (const float*)d_in[4];
  const float* Wr1  = (const float*)d_in[5];
  const float* br1  = (const float*)d_in[6];
  const float* We1  = (const float*)d_in[7];
  const float* att1 = (const float*)d_in[8];
  const float* bias1= (const float*)d_in[9];
  const float* Wl2  = (const float*)d_in[10];
  const float* bl2  = (const float*)d_in[11];
  const float* Wr2  = (const float*)d_in[12];
  const float* br2  = (const float*)d_in[13];
  const float* We2  = (const float*)d_in[14];
  const float* att2 = (const float*)d_in[15];
  const float* bias2= (const float*)d_in[16];

  float* out = (float*)d_out;
  float* ws  = (float*)d_ws;

  float* elog = ws;                                    // NE*4 f32
  unsigned short* xlb  = (unsigned short*)(elog + (size_t)NE * 4); // NN*256
  unsigned short* xrb  = xlb + (size_t)NN * 256;       // NN*256
  unsigned short* wef1 = xrb + (size_t)NN * 256;       // 16384
  unsigned short* wef2 = wef1 + 16384;                 // 16384
  unsigned short* wlf1 = wef2 + 16384;                 // 32768
  unsigned short* wrf1 = wlf1 + 32768;                 // 32768
  unsigned short* wlf2 = wrf1 + 32768;                 // 65536
  unsigned short* wrf2 = wlf2 + 65536;                 // 65536
  int* cur       = (int*)(wrf2 + 65536);               // NN
  int* row_start = cur + NN;                           // NN+1
  int* bsum      = row_start + NN + 1;                 // 64
  int* eid       = bsum + 64;                          // NE
  int* ssrc      = eid + NE;                           // NE
  int* sdst      = ssrc + NE;                          // NE
  unsigned short* eab = (unsigned short*)(sdst + NE);  // NE*64 bf16 (optional)
  const size_t need_eab =
      ((char*)(eab + (size_t)NE * 64)) - (char*)d_ws;
  const bool use_eab = ws_size >= need_eab;
  float* h1 = out;  // d_out doubles as h1

  const int* src = ei;
  const int* dst = ei + NE;

  const int ggrid = (NN + 63) / 64;      // 782
  const int egrid = NE / 32;             // 25000
  const int epb   = (NE + 255) / 256;
  const int agrid = NN / 4;              // 12500
  const int nb    = (NN + 1023) / 1024;  // 49

  // ---- prep: CSR + bf16 weight tables (+ eab) ----
  hipMemsetAsync(cur, 0, NN * sizeof(int), stream);
  conv_all<<<dim3(256, 6), 256, 0, stream>>>(We1, wef1, We2, wef2,
                                             Wl1, wlf1, Wr1, wrf1,
                                             Wl2, wlf2, Wr2, wrf2);
  dst_hist<<<epb, 256, 0, stream>>>(dst, cur);
  scan_bsum<<<nb, 1024, 0, stream>>>(cur, bsum, NN);
  scan_bsum_scan<<<1, 64, 0, stream>>>(bsum, row_start, nb, NN);
  scan_apply<<<nb, 1024, 0, stream>>>(cur, bsum, row_start, NN);
  bucket_fill<<<epb, 256, 0, stream>>>(src, dst, cur, eid, ssrc, sdst);
  if (use_eab)
    conv_eab<<<NE * 16 / 256, 256, 0, stream>>>(ea, eid, eab);

  // ---- layer 1 ----
  gemm_mfma2<4><<<ggrid, 256, 0, stream>>>(x, wlf1, bl1, xlb, wrf1, br1, xrb);
  if (use_eab)
    edge_logits_swap<1><<<egrid, 128, 0, stream>>>(ea, eab, wef1, xlb, xrb,
                                                   att1, eid, ssrc, sdst, elog);
  else
    edge_logits_swap<0><<<egrid, 128, 0, stream>>>(ea, eab, wef1, xlb, xrb,
                                                   att1, eid, ssrc, sdst, elog);
  aggregate<<<agrid, 256, 0, stream>>>(xlb, elog, ssrc, row_start, bias1, h1);

  // ---- layer 2 ----
  gemm_mfma2<8><<<ggrid, 256, 0, stream>>>(h1, wlf2, bl2, xlb, wrf2, br2, xrb);
  if (use_eab)
    edge_logits_swap<1><<<egrid, 128, 0, stream>>>(ea, eab, wef2, xlb, xrb,
                                                   att2, eid, ssrc, sdst, elog);
  else
    edge_logits_swap<0><<<egrid, 128, 0, stream>>>(ea, eab, wef2, xlb, xrb,
                                                   att2, eid, ssrc, sdst, elog);
  aggregate<<<agrid, 256, 0, stream>>>(xlb, elog, ssrc, row_start, bias2, out);
}

// Round 16
// 679.907 us; speedup vs baseline: 1.0516x; 1.0200x over previous
//
#include <hip/hip_runtime.h>
#include <math.h>

#define NN 50000
#define NE 800000

#define LRELU(v) fmaxf((v), 0.2f * (v))

typedef __attribute__((ext_vector_type(4))) float f32x4;
typedef __attribute__((ext_vector_type(8))) short bf16x8;

static __device__ __forceinline__ unsigned short f2bf(float f) {
  union { float f; unsigned int i; } c; c.f = f;
  unsigned int r = c.i + 0x7fff + ((c.i >> 16) & 1);   // RNE
  return (unsigned short)(r >> 16);
}
static __device__ __forceinline__ float bflo(unsigned int u) {
  union { unsigned int i; float f; } c; c.i = u << 16; return c.f;
}
static __device__ __forceinline__ float bfhi(unsigned int u) {
  union { unsigned int i; float f; } c; c.i = u & 0xffff0000u; return c.f;
}

// ---------------------------------------------------------------------------
// conv_all: all 6 bf16 weight tables in ONE dispatch (see R15).
// ---------------------------------------------------------------------------
__global__ __launch_bounds__(256)
void conv_all(const float* __restrict__ We1, unsigned short* __restrict__ wef1,
              const float* __restrict__ We2, unsigned short* __restrict__ wef2,
              const float* __restrict__ Wl1, unsigned short* __restrict__ wlf1,
              const float* __restrict__ Wr1, unsigned short* __restrict__ wrf1,
              const float* __restrict__ Wl2, unsigned short* __restrict__ wlf2,
              const float* __restrict__ Wr2, unsigned short* __restrict__ wrf2) {
  const int y = blockIdx.y;
  const int g = blockIdx.x * 256 + threadIdx.x;
  if (y < 2) {
    if (g >= 16384) return;
    const float* We = y ? We2 : We1;
    unsigned short* wef = y ? wef2 : wef1;
    const int j = g & 7;
    const int l = (g >> 3) & 63;
    const int t = g >> 9;
    const int n = t & 15, half = t >> 4;
    const int k = half * 32 + (l >> 4) * 8 + j;
    const int c = ((l & 15) >> 2) * 64 + n * 4 + (l & 3);
    wef[g] = f2bf(We[(size_t)k * 256 + c]);
  } else {
    const int K = (y < 4) ? 128 : 256;
    if (g >= K * 256) return;
    const float* W = (y == 2) ? Wl1 : (y == 3) ? Wr1 : (y == 4) ? Wl2 : Wr2;
    unsigned short* wf = (y == 2) ? wlf1 : (y == 3) ? wrf1
                       : (y == 4) ? wlf2 : wrf2;
    const int j = g & 7;
    const int l = (g >> 3) & 63;
    const int fn = g >> 9;
    const int n = fn & 15, ks = fn >> 4;
    const int k = ks * 32 + (l >> 4) * 8 + j;
    const int c = n * 16 + (l & 15);
    wf[g] = f2bf(W[(size_t)k * 256 + c]);
  }
}

// ---------------------------------------------------------------------------
// Fused MFMA node GEMM: xl = bf16(A@Wl + bl), xr = bf16(A@Wr + br).
// BF=1: A is bf16 row-major (layer-2 path, h1b); BF=0: A is fp32 (layer-1, x).
// ---------------------------------------------------------------------------
template <int KS, int BF>   // KS = K/32
__global__ __launch_bounds__(256)
void gemm_mfma2(const void* __restrict__ Av,
                const unsigned short* __restrict__ wfl,
                const float* __restrict__ bl, unsigned short* __restrict__ outl,
                const unsigned short* __restrict__ wfr,
                const float* __restrict__ br, unsigned short* __restrict__ outr) {
  const int tid = threadIdx.x;
  const int w = tid >> 6, l = tid & 63;
  const int lid = l & 15, lg = l >> 4;
  const int row  = blockIdx.x * 64 + w * 16 + lid;
  const bool rowok = row < NN;
  const int rowv = rowok ? row : NN - 1;
  const int K = KS * 32;

  bf16x8 bfr[KS];
  if (BF) {
    const unsigned short* A = (const unsigned short*)Av;
    const unsigned short* ap = A + (size_t)rowv * K + lg * 8;
#pragma unroll
    for (int ks = 0; ks < KS; ++ks)
      bfr[ks] = *(const bf16x8*)(ap + ks * 32);
  } else {
    const float* A = (const float*)Av;
    const float* ap = A + (size_t)rowv * K + lg * 8;
#pragma unroll
    for (int ks = 0; ks < KS; ++ks) {
      const float4 v0 = *(const float4*)(ap + ks * 32);
      const float4 v1 = *(const float4*)(ap + ks * 32 + 4);
      bf16x8 b;
      b[0]=f2bf(v0.x); b[1]=f2bf(v0.y); b[2]=f2bf(v0.z); b[3]=f2bf(v0.w);
      b[4]=f2bf(v1.x); b[5]=f2bf(v1.y); b[6]=f2bf(v1.z); b[7]=f2bf(v1.w);
      bfr[ks] = b;
    }
  }

  f32x4 acc[16];

  // ---- pass 1: Wl ----
#pragma unroll
  for (int n = 0; n < 16; ++n) acc[n] = (f32x4){0.f, 0.f, 0.f, 0.f};
#pragma unroll
  for (int ks = 0; ks < KS; ++ks)
#pragma unroll
    for (int n = 0; n < 16; ++n) {
      const bf16x8 a = *(const bf16x8*)(wfl + ((size_t)(ks * 16 + n) * 64 + l) * 8);
      acc[n] = __builtin_amdgcn_mfma_f32_16x16x32_bf16(a, bfr[ks], acc[n], 0, 0, 0);
    }
  if (rowok) {
#pragma unroll
    for (int n = 0; n < 16; ++n) {
      const int c0 = n * 16 + lg * 4;
      const float4 bv = *(const float4*)(bl + c0);
      ushort4 o;
      o.x = f2bf(acc[n][0] + bv.x); o.y = f2bf(acc[n][1] + bv.y);
      o.z = f2bf(acc[n][2] + bv.z); o.w = f2bf(acc[n][3] + bv.w);
      *(ushort4*)(outl + (size_t)row * 256 + c0) = o;
    }
  }

  // ---- pass 2: Wr (reuse A frags) ----
#pragma unroll
  for (int n = 0; n < 16; ++n) acc[n] = (f32x4){0.f, 0.f, 0.f, 0.f};
#pragma unroll
  for (int ks = 0; ks < KS; ++ks)
#pragma unroll
    for (int n = 0; n < 16; ++n) {
      const bf16x8 a = *(const bf16x8*)(wfr + ((size_t)(ks * 16 + n) * 64 + l) * 8);
      acc[n] = __builtin_amdgcn_mfma_f32_16x16x32_bf16(a, bfr[ks], acc[n], 0, 0, 0);
    }
  if (rowok) {
#pragma unroll
    for (int n = 0; n < 16; ++n) {
      const int c0 = n * 16 + lg * 4;
      const float4 bv = *(const float4*)(br + c0);
      ushort4 o;
      o.x = f2bf(acc[n][0] + bv.x); o.y = f2bf(acc[n][1] + bv.y);
      o.z = f2bf(acc[n][2] + bv.z); o.w = f2bf(acc[n][3] + bv.w);
      *(ushort4*)(outr + (size_t)row * 256 + c0) = o;
    }
  }
}

// ---------------------------------------------------------------------------
// CSR build
// ---------------------------------------------------------------------------
__global__ __launch_bounds__(256)
void dst_hist(const int* __restrict__ dst, int* __restrict__ cnt) {
  const int e = blockIdx.x * 256 + threadIdx.x;
  if (e < NE) atomicAdd(&cnt[dst[e]], 1);
}

__global__ __launch_bounds__(1024)
void scan_bsum(const int* __restrict__ cnt, int* __restrict__ bsum, int n) {
  __shared__ int wsum[16];
  const int tid = threadIdx.x;
  const int lane = tid & 63, wid = tid >> 6;
  const int i = blockIdx.x * 1024 + tid;
  int v = (i < n) ? cnt[i] : 0;
#pragma unroll
  for (int off = 32; off >= 1; off >>= 1) v += __shfl_xor(v, off);
  if (lane == 0) wsum[wid] = v;
  __syncthreads();
  if (tid == 0) {
    int s = 0;
#pragma unroll
    for (int k = 0; k < 16; ++k) s += wsum[k];
    bsum[blockIdx.x] = s;
  }
}

__global__ __launch_bounds__(64)
void scan_bsum_scan(int* __restrict__ bsum, int* __restrict__ row_start,
                    int nb, int n) {
  const int lane = threadIdx.x;
  const int v = (lane < nb) ? bsum[lane] : 0;
  int incl = v;
#pragma unroll
  for (int off = 1; off < 64; off <<= 1) {
    const int t = __shfl_up(incl, off);
    if (lane >= off) incl += t;
  }
  if (lane < nb) bsum[lane] = incl - v;
  if (lane == 63) row_start[n] = incl;
}

__global__ __launch_bounds__(1024)
void scan_apply(int* __restrict__ cnt, const int* __restrict__ bsum,
                int* __restrict__ row_start, int n) {
  __shared__ int wsum[16];
  __shared__ int woff[16];
  const int tid = threadIdx.x;
  const int lane = tid & 63, wid = tid >> 6;
  const int i = blockIdx.x * 1024 + tid;
  const int v = (i < n) ? cnt[i] : 0;
  int incl = v;
#pragma unroll
  for (int off = 1; off < 64; off <<= 1) {
    const int t = __shfl_up(incl, off);
    if (lane >= off) incl += t;
  }
  if (lane == 63) wsum[wid] = incl;
  __syncthreads();
  if (wid == 0) {
    const int s = (lane < 16) ? wsum[lane] : 0;
    int si = s;
#pragma unroll
    for (int off = 1; off < 16; off <<= 1) {
      const int t = __shfl_up(si, off);
      if (lane >= off) si += t;
    }
    if (lane < 16) woff[lane] = si - s;
  }
  __syncthreads();
  if (i < n) {
    const int excl = bsum[blockIdx.x] + woff[wid] + incl - v;
    row_start[i] = excl;
    cnt[i] = excl;
  }
}

__global__ __launch_bounds__(256)
void bucket_fill(const int* __restrict__ src, const int* __restrict__ dst,
                 int* __restrict__ cur, int* __restrict__ eid,
                 int* __restrict__ ssrc, int* __restrict__ sdst) {
  const int e = blockIdx.x * 256 + threadIdx.x;
  if (e < NE) {
    const int d = dst[e];
    const int p = atomicAdd(&cur[d], 1);
    eid[p] = e;
    ssrc[p] = src[e];
    sdst[p] = d;
  }
}

// ---------------------------------------------------------------------------
// eab prep: eab[p][c] = bf16(ea[eid[p]][c]).
// ---------------------------------------------------------------------------
__global__ __launch_bounds__(256)
void conv_eab(const float* __restrict__ ea, const int* __restrict__ eid,
              unsigned short* __restrict__ eab) {
  const int g = blockIdx.x * 256 + threadIdx.x;
  const int p = g >> 4, c4 = (g & 15) * 4;
  const int e = eid[p];
  const float4 v = *(const float4*)(ea + (size_t)e * 64 + c4);
  ushort4 o;
  o.x = f2bf(v.x); o.y = f2bf(v.y); o.z = f2bf(v.z); o.w = f2bf(v.w);
  *(ushort4*)(eab + (size_t)p * 64 + c4) = o;
}

// ---------------------------------------------------------------------------
// per-tile epilogue: MFMA (wef frags x edge frags) + lrelu/att dot over the
// lane's contiguous 64 cols. xlp = LDS, xrp = global (dst-clustered).
// ---------------------------------------------------------------------------
static __device__ __forceinline__ float edge_epilogue(
    const unsigned short* __restrict__ xlp,
    const unsigned short* __restrict__ xrp,
    const float* __restrict__ attp,
    const unsigned short* __restrict__ wef,
    bf16x8 f0, bf16x8 f1, int l) {
  float ph = 0.f;
#pragma unroll
  for (int nn = 0; nn < 8; ++nn) {
    const bf16x8 w00 = *(const bf16x8*)(wef + ((size_t)(0  + 2 * nn)     * 64 + l) * 8);
    const bf16x8 w01 = *(const bf16x8*)(wef + ((size_t)(16 + 2 * nn)     * 64 + l) * 8);
    const bf16x8 w10 = *(const bf16x8*)(wef + ((size_t)(0  + 2 * nn + 1) * 64 + l) * 8);
    const bf16x8 w11 = *(const bf16x8*)(wef + ((size_t)(16 + 2 * nn + 1) * 64 + l) * 8);

    f32x4 a0 = (f32x4){0.f,0.f,0.f,0.f}, a1 = (f32x4){0.f,0.f,0.f,0.f};
    a0 = __builtin_amdgcn_mfma_f32_16x16x32_bf16(w00, f0, a0, 0, 0, 0);
    a0 = __builtin_amdgcn_mfma_f32_16x16x32_bf16(w01, f1, a0, 0, 0, 0);
    a1 = __builtin_amdgcn_mfma_f32_16x16x32_bf16(w10, f0, a1, 0, 0, 0);
    a1 = __builtin_amdgcn_mfma_f32_16x16x32_bf16(w11, f1, a1, 0, 0, 0);

    const int c0 = nn * 8;
    const uint4 xu = *(const uint4*)(xlp + c0);
    const uint4 ru = *(const uint4*)(xrp + c0);
    const float4 at0 = *(const float4*)(attp + c0);
    const float4 at1 = *(const float4*)(attp + c0 + 4);
    float v;
    v = a0[0] + bflo(xu.x) + bflo(ru.x); v = LRELU(v); ph += v * at0.x;
    v = a0[1] + bfhi(xu.x) + bfhi(ru.x); v = LRELU(v); ph += v * at0.y;
    v = a0[2] + bflo(xu.y) + bflo(ru.y); v = LRELU(v); ph += v * at0.z;
    v = a0[3] + bfhi(xu.y) + bfhi(ru.y); v = LRELU(v); ph += v * at0.w;
    v = a1[0] + bflo(xu.z) + bflo(ru.z); v = LRELU(v); ph += v * at1.x;
    v = a1[1] + bfhi(xu.z) + bfhi(ru.z); v = LRELU(v); ph += v * at1.y;
    v = a1[2] + bflo(xu.w) + bflo(ru.w); v = LRELU(v); ph += v * at1.z;
    v = a1[3] + bfhi(xu.w) + bfhi(ru.w); v = LRELU(v); ph += v * at1.w;
  }
  return ph;
}

// ---------------------------------------------------------------------------
// Edge kernel, T14 2-tile pipeline: each wave owns 32 CSR positions (2 tiles
// of 16). Tile B's gathers are issued into registers BEFORE tile A's epilogue
// (HBM latency hides under A's MFMA/VALU); B's LDS write happens after A's
// LDS reads (wave-private LDS, per-wave in-order DS => single buffer safe).
// ---------------------------------------------------------------------------
template <int EAB>
__global__ __launch_bounds__(128)
void edge_logits_swap(const float* __restrict__ ea,
                      const unsigned short* __restrict__ eab,
                      const unsigned short* __restrict__ wef,  // [2][16][64][8]
                      const unsigned short* __restrict__ xlb,
                      const unsigned short* __restrict__ xrb,
                      const float* __restrict__ att,
                      const int* __restrict__ eid,
                      const int* __restrict__ ssrc, const int* __restrict__ sdst,
                      float* __restrict__ elog) {
  __shared__ unsigned short sxl[2][16 * 264];   // one buffer per wave

  const int tid = threadIdx.x;
  const int w = tid >> 6, l = tid & 63;
  const int lid = l & 15, lg = l >> 4;
  const int base = (blockIdx.x * 2 + w) * 32;   // wave: tiles A=[base,+16), B=[base+16,+32)
  const int pA = base + lid;
  const int pB = base + 16 + lid;

  unsigned short* myxl = sxl[w];
  const int srow_r = l >> 5;     // my staged row parity
  const int unit   = l & 31;     // my 16B unit within row

  // ---- tile A: frags + dst + gather into regs ----
  bf16x8 fA0, fA1;
  if (EAB) {
    fA0 = *(const bf16x8*)(eab + (size_t)pA * 64 + lg * 8);
    fA1 = *(const bf16x8*)(eab + (size_t)pA * 64 + 32 + lg * 8);
  } else {
    const int e = eid[pA];
    const float* ap = ea + (size_t)e * 64 + lg * 8;
    const float4 v00 = *(const float4*)(ap);
    const float4 v01 = *(const float4*)(ap + 4);
    const float4 v10 = *(const float4*)(ap + 32);
    const float4 v11 = *(const float4*)(ap + 36);
    fA0[0]=f2bf(v00.x); fA0[1]=f2bf(v00.y); fA0[2]=f2bf(v00.z); fA0[3]=f2bf(v00.w);
    fA0[4]=f2bf(v01.x); fA0[5]=f2bf(v01.y); fA0[6]=f2bf(v01.z); fA0[7]=f2bf(v01.w);
    fA1[0]=f2bf(v10.x); fA1[1]=f2bf(v10.y); fA1[2]=f2bf(v10.z); fA1[3]=f2bf(v10.w);
    fA1[4]=f2bf(v11.x); fA1[5]=f2bf(v11.y); fA1[6]=f2bf(v11.z); fA1[7]=f2bf(v11.w);
  }
  const int dA = sdst[pA];

  uint4 gA[8];
#pragma unroll
  for (int i = 0; i < 8; ++i) {
    const int row = i * 2 + srow_r;
    const int srow = ssrc[base + row];
    gA[i] = *(const uint4*)(xlb + (size_t)srow * 256 + unit * 8);
  }

  // ---- tile B: frags + dst + gather into regs (in flight over epilogue A) --
  bf16x8 fB0, fB1;
  if (EAB) {
    fB0 = *(const bf16x8*)(eab + (size_t)pB * 64 + lg * 8);
    fB1 = *(const bf16x8*)(eab + (size_t)pB * 64 + 32 + lg * 8);
  } else {
    const int e = eid[pB];
    const float* ap = ea + (size_t)e * 64 + lg * 8;
    const float4 v00 = *(const float4*)(ap);
    const float4 v01 = *(const float4*)(ap + 4);
    const float4 v10 = *(const float4*)(ap + 32);
    const float4 v11 = *(const float4*)(ap + 36);
    fB0[0]=f2bf(v00.x); fB0[1]=f2bf(v00.y); fB0[2]=f2bf(v00.z); fB0[3]=f2bf(v00.w);
    fB0[4]=f2bf(v01.x); fB0[5]=f2bf(v01.y); fB0[6]=f2bf(v01.z); fB0[7]=f2bf(v01.w);
    fB1[0]=f2bf(v10.x); fB1[1]=f2bf(v10.y); fB1[2]=f2bf(v10.z); fB1[3]=f2bf(v10.w);
    fB1[4]=f2bf(v11.x); fB1[5]=f2bf(v11.y); fB1[6]=f2bf(v11.z); fB1[7]=f2bf(v11.w);
  }
  const int dB = sdst[pB];

  uint4 gB[8];
#pragma unroll
  for (int i = 0; i < 8; ++i) {
    const int row = i * 2 + srow_r;
    const int srow = ssrc[base + 16 + row];
    gB[i] = *(const uint4*)(xlb + (size_t)srow * 256 + unit * 8);
  }

  // ---- stage A + epilogue A (B's gathers remain in flight) ----
#pragma unroll
  for (int i = 0; i < 8; ++i) {
    const int row = i * 2 + srow_r;
    *(uint4*)&myxl[row * 264 + unit * 8] = gA[i];
  }
  const float phA = edge_epilogue(myxl + lid * 264 + lg * 64,
                                  xrb + (size_t)dA * 256 + lg * 64,
                                  att + lg * 64, wef, fA0, fA1, l);
  elog[(size_t)pA * 4 + lg] = expf(phA);

  // ---- stage B (ordered after A's LDS reads) + epilogue B ----
#pragma unroll
  for (int i = 0; i < 8; ++i) {
    const int row = i * 2 + srow_r;
    *(uint4*)&myxl[row * 264 + unit * 8] = gB[i];
  }
  const float phB = edge_epilogue(myxl + lid * 264 + lg * 64,
                                  xrb + (size_t)dB * 256 + lg * 64,
                                  att + lg * 64, wef, fB0, fB1, l);
  elog[(size_t)pB * 4 + lg] = expf(phB);
}

// ---------------------------------------------------------------------------
// Aggregation (R13 pattern): one wave per dst node, 4 nodes/block; 4-deep
// unrolled loads. FINAL=1 -> fp32 to d_out; FINAL=0 -> bf16 to h1b.
// ---------------------------------------------------------------------------
template <int FINAL>
__global__ __launch_bounds__(256)
void aggregate(const unsigned short* __restrict__ xlb,
               const float* __restrict__ elog,
               const int* __restrict__ ssrc, const int* __restrict__ row_start,
               const float* __restrict__ bias, float* __restrict__ outf,
               unsigned short* __restrict__ outb) {
  const int wid  = threadIdx.x >> 6;
  const int lane = threadIdx.x & 63;
  const int d    = blockIdx.x * 4 + wid;
  const int h = lane >> 4;
  const int c = lane * 4;
  float ax = 0.f, ay = 0.f, az = 0.f, aw = 0.f;
  float dtot = 0.f;
  const int beg = row_start[d], end = row_start[d + 1];
  int p = beg;
  for (; p + 4 <= end; p += 4) {
    const float e0 = elog[(size_t)(p + 0) * 4 + h];
    const float e1 = elog[(size_t)(p + 1) * 4 + h];
    const float e2 = elog[(size_t)(p + 2) * 4 + h];
    const float e3 = elog[(size_t)(p + 3) * 4 + h];
    const int s0 = ssrc[p + 0], s1 = ssrc[p + 1];
    const int s2 = ssrc[p + 2], s3 = ssrc[p + 3];
    const uint2 x0 = *(const uint2*)(xlb + (size_t)s0 * 256 + c);
    const uint2 x1 = *(const uint2*)(xlb + (size_t)s1 * 256 + c);
    const uint2 x2 = *(const uint2*)(xlb + (size_t)s2 * 256 + c);
    const uint2 x3 = *(const uint2*)(xlb + (size_t)s3 * 256 + c);
    ax += e0*bflo(x0.x) + e1*bflo(x1.x) + e2*bflo(x2.x) + e3*bflo(x3.x);
    ay += e0*bfhi(x0.x) + e1*bfhi(x1.x) + e2*bfhi(x2.x) + e3*bfhi(x3.x);
    az += e0*bflo(x0.y) + e1*bflo(x1.y) + e2*bflo(x2.y) + e3*bflo(x3.y);
    aw += e0*bfhi(x0.y) + e1*bfhi(x1.y) + e2*bfhi(x2.y) + e3*bfhi(x3.y);
    dtot += e0 + e1 + e2 + e3;
  }
  for (; p < end; ++p) {
    const float ev = elog[(size_t)p * 4 + h];
    const int s = ssrc[p];
    const uint2 xv = *(const uint2*)(xlb + (size_t)s * 256 + c);
    ax += ev * bflo(xv.x); ay += ev * bfhi(xv.x);
    az += ev * bflo(xv.y); aw += ev * bfhi(xv.y);
    dtot += ev;
  }
  const float inv = 1.f / (dtot + 1e-16f);
  const float4 bv = *(const float4*)(bias + c);
  float4 o;
  o.x = bv.x + ax * inv; o.y = bv.y + ay * inv;
  o.z = bv.z + az * inv; o.w = bv.w + aw * inv;
  if (FINAL) {
    *(float4*)(outf + (size_t)d * 256 + c) = o;
  } else {
    ushort4 ob;
    ob.x = f2bf(o.x); ob.y = f2bf(o.y); ob.z = f2bf(o.z); ob.w = f2bf(o.w);
    *(ushort4*)(outb + (size_t)d * 256 + c) = ob;
  }
}

extern "C" void kernel_launch(void* const* d_in, const int* in_sizes, int n_in,
                              void* d_out, int out_size, void* d_ws, size_t ws_size,
                              hipStream_t stream) {
  const float* x    = (const float*)d_in[0];
  const int*   ei   = (const int*)d_in[1];
  const float* ea   = (const float*)d_in[2];
  const float* Wl1  = (const float*)d_in[3];
  const float* bl1  = (const float*)d_in[4];
  const float* Wr1  = (const float*)d_in[5];
  const float* br1  = (const float*)d_in[6];
  const float* We1  = (const float*)d_in[7];
  const float* att1 = (const float*)d_in[8];
  const float* bias1= (const float*)d_in[9];
  const float* Wl2  = (const float*)d_in[10];
  const float* bl2  = (const float*)d_in[11];
  const float* Wr2  = (const float*)d_in[12];
  const float* br2  = (const float*)d_in[13];
  const float* We2  = (const float*)d_in[14];
  const float* att2 = (const float*)d_in[15];
  const float* bias2= (const float*)d_in[16];

  float* out = (float*)d_out;
  float* ws  = (float*)d_ws;

  float* elog = ws;                                    // NE*4 f32
  unsigned short* xlb  = (unsigned short*)(elog + (size_t)NE * 4); // NN*256
  unsigned short* xrb  = xlb + (size_t)NN * 256;       // NN*256
  unsigned short* h1b  = xrb + (size_t)NN * 256;       // NN*256 (layer-1 out)
  unsigned short* wef1 = h1b + (size_t)NN * 256;       // 16384
  unsigned short* wef2 = wef1 + 16384;                 // 16384
  unsigned short* wlf1 = wef2 + 16384;                 // 32768
  unsigned short* wrf1 = wlf1 + 32768;                 // 32768
  unsigned short* wlf2 = wrf1 + 32768;                 // 65536
  unsigned short* wrf2 = wlf2 + 65536;                 // 65536
  int* cur       = (int*)(wrf2 + 65536);               // NN
  int* row_start = cur + NN;                           // NN+1
  int* bsum      = row_start + NN + 1;                 // 64
  int* eid       = bsum + 64;                          // NE
  int* ssrc      = eid + NE;                           // NE
  int* sdst      = ssrc + NE;                          // NE
  unsigned short* eab = (unsigned short*)(sdst + NE);  // NE*64 bf16 (optional)
  const size_t need_eab =
      ((char*)(eab + (size_t)NE * 64)) - (char*)d_ws;
  const bool use_eab = ws_size >= need_eab;

  const int* src = ei;
  const int* dst = ei + NE;

  const int ggrid = (NN + 63) / 64;      // 782
  const int egrid = NE / 64;             // 12500 (2 waves x 32 / block)
  const int epb   = (NE + 255) / 256;
  const int agrid = NN / 4;              // 12500
  const int nb    = (NN + 1023) / 1024;  // 49

  // ---- prep: CSR + bf16 weight tables (+ eab) ----
  hipMemsetAsync(cur, 0, NN * sizeof(int), stream);
  conv_all<<<dim3(256, 6), 256, 0, stream>>>(We1, wef1, We2, wef2,
                                             Wl1, wlf1, Wr1, wrf1,
                                             Wl2, wlf2, Wr2, wrf2);
  dst_hist<<<epb, 256, 0, stream>>>(dst, cur);
  scan_bsum<<<nb, 1024, 0, stream>>>(cur, bsum, NN);
  scan_bsum_scan<<<1, 64, 0, stream>>>(bsum, row_start, nb, NN);
  scan_apply<<<nb, 1024, 0, stream>>>(cur, bsum, row_start, NN);
  bucket_fill<<<epb, 256, 0, stream>>>(src, dst, cur, eid, ssrc, sdst);
  if (use_eab)
    conv_eab<<<NE * 16 / 256, 256, 0, stream>>>(ea, eid, eab);

  // ---- layer 1 ----
  gemm_mfma2<4, 0><<<ggrid, 256, 0, stream>>>(x, wlf1, bl1, xlb,
                                              wrf1, br1, xrb);
  if (use_eab)
    edge_logits_swap<1><<<egrid, 128, 0, stream>>>(ea, eab, wef1, xlb, xrb,
                                                   att1, eid, ssrc, sdst, elog);
  else
    edge_logits_swap<0><<<egrid, 128, 0, stream>>>(ea, eab, wef1, xlb, xrb,
                                                   att1, eid, ssrc, sdst, elog);
  aggregate<0><<<agrid, 256, 0, stream>>>(xlb, elog, ssrc, row_start, bias1,
                                          nullptr, h1b);

  // ---- layer 2 ----
  gemm_mfma2<8, 1><<<ggrid, 256, 0, stream>>>(h1b, wlf2, bl2, xlb,
                                              wrf2, br2, xrb);
  if (use_eab)
    edge_logits_swap<1><<<egrid, 128, 0, stream>>>(ea, eab, wef2, xlb, xrb,
                                                   att2, eid, ssrc, sdst, elog);
  else
    edge_logits_swap<0><<<egrid, 128, 0, stream>>>(ea, eab, wef2, xlb, xrb,
                                                   att2, eid, ssrc, sdst, elog);
  aggregate<1><<<agrid, 256, 0, stream>>>(xlb, elog, ssrc, row_start, bias2,
                                          out, nullptr);
}

// Round 17
// 603.513 us; speedup vs baseline: 1.1847x; 1.1266x over previous
//
#include <hip/hip_runtime.h>
#include <math.h>

#define NN 50000
#define NE 800000

#define LRELU(v) fmaxf((v), 0.2f * (v))

typedef __attribute__((ext_vector_type(4))) float f32x4;
typedef __attribute__((ext_vector_type(8))) short bf16x8;

static __device__ __forceinline__ unsigned short f2bf(float f) {
  union { float f; unsigned int i; } c; c.f = f;
  unsigned int r = c.i + 0x7fff + ((c.i >> 16) & 1);   // RNE
  return (unsigned short)(r >> 16);
}
static __device__ __forceinline__ float bflo(unsigned int u) {
  union { unsigned int i; float f; } c; c.i = u << 16; return c.f;
}
static __device__ __forceinline__ float bfhi(unsigned int u) {
  union { unsigned int i; float f; } c; c.i = u & 0xffff0000u; return c.f;
}

// ---------------------------------------------------------------------------
// conv_all: all 6 bf16 weight tables in ONE dispatch.
// ---------------------------------------------------------------------------
__global__ __launch_bounds__(256)
void conv_all(const float* __restrict__ We1, unsigned short* __restrict__ wef1,
              const float* __restrict__ We2, unsigned short* __restrict__ wef2,
              const float* __restrict__ Wl1, unsigned short* __restrict__ wlf1,
              const float* __restrict__ Wr1, unsigned short* __restrict__ wrf1,
              const float* __restrict__ Wl2, unsigned short* __restrict__ wlf2,
              const float* __restrict__ Wr2, unsigned short* __restrict__ wrf2) {
  const int y = blockIdx.y;
  const int g = blockIdx.x * 256 + threadIdx.x;
  if (y < 2) {
    if (g >= 16384) return;
    const float* We = y ? We2 : We1;
    unsigned short* wef = y ? wef2 : wef1;
    const int j = g & 7;
    const int l = (g >> 3) & 63;
    const int t = g >> 9;
    const int n = t & 15, half = t >> 4;
    const int k = half * 32 + (l >> 4) * 8 + j;
    const int c = ((l & 15) >> 2) * 64 + n * 4 + (l & 3);
    wef[g] = f2bf(We[(size_t)k * 256 + c]);
  } else {
    const int K = (y < 4) ? 128 : 256;
    if (g >= K * 256) return;
    const float* W = (y == 2) ? Wl1 : (y == 3) ? Wr1 : (y == 4) ? Wl2 : Wr2;
    unsigned short* wf = (y == 2) ? wlf1 : (y == 3) ? wrf1
                       : (y == 4) ? wlf2 : wrf2;
    const int j = g & 7;
    const int l = (g >> 3) & 63;
    const int fn = g >> 9;
    const int n = fn & 15, ks = fn >> 4;
    const int k = ks * 32 + (l >> 4) * 8 + j;
    const int c = n * 16 + (l & 15);
    wf[g] = f2bf(W[(size_t)k * 256 + c]);
  }
}

// ---------------------------------------------------------------------------
// MFMA node GEMM, 4-way split: blockIdx.y = (col-half << 1) | matrix.
// Each block: 64 rows x 128 cols of one output. acc[8] (32 VGPR), grid
// 782x4 = 3128 blocks -> 12 blocks/CU pipeline depth (fixes R13-R16's
// 3-waves/SIMD whole-grid residency stall).
// BF=1: A bf16 (layer 2, h1b); BF=0: A fp32 (layer 1, x).
// ---------------------------------------------------------------------------
template <int KS, int BF>   // KS = K/32
__global__ __launch_bounds__(256)
void gemm_mfma4(const void* __restrict__ Av,
                const unsigned short* __restrict__ wf0,
                const float* __restrict__ b0, unsigned short* __restrict__ out0,
                const unsigned short* __restrict__ wf1,
                const float* __restrict__ b1, unsigned short* __restrict__ out1) {
  const int mat = blockIdx.y & 1;
  const int nh  = blockIdx.y >> 1;          // column half: n in [nh*8, nh*8+8)
  const unsigned short* wf = mat ? wf1 : wf0;
  const float* bias        = mat ? b1 : b0;
  unsigned short* outb     = mat ? out1 : out0;

  const int tid = threadIdx.x;
  const int w = tid >> 6, l = tid & 63;
  const int lid = l & 15, lg = l >> 4;
  const int row  = blockIdx.x * 64 + w * 16 + lid;
  const bool rowok = row < NN;
  const int rowv = rowok ? row : NN - 1;
  const int K = KS * 32;

  bf16x8 bfr[KS];
  if (BF) {
    const unsigned short* A = (const unsigned short*)Av;
    const unsigned short* ap = A + (size_t)rowv * K + lg * 8;
#pragma unroll
    for (int ks = 0; ks < KS; ++ks)
      bfr[ks] = *(const bf16x8*)(ap + ks * 32);
  } else {
    const float* A = (const float*)Av;
    const float* ap = A + (size_t)rowv * K + lg * 8;
#pragma unroll
    for (int ks = 0; ks < KS; ++ks) {
      const float4 v0 = *(const float4*)(ap + ks * 32);
      const float4 v1 = *(const float4*)(ap + ks * 32 + 4);
      bf16x8 b;
      b[0]=f2bf(v0.x); b[1]=f2bf(v0.y); b[2]=f2bf(v0.z); b[3]=f2bf(v0.w);
      b[4]=f2bf(v1.x); b[5]=f2bf(v1.y); b[6]=f2bf(v1.z); b[7]=f2bf(v1.w);
      bfr[ks] = b;
    }
  }

  f32x4 acc[8];
#pragma unroll
  for (int n8 = 0; n8 < 8; ++n8) acc[n8] = (f32x4){0.f, 0.f, 0.f, 0.f};

#pragma unroll
  for (int ks = 0; ks < KS; ++ks)
#pragma unroll
    for (int n8 = 0; n8 < 8; ++n8) {
      const int n = nh * 8 + n8;
      const bf16x8 a = *(const bf16x8*)(wf + ((size_t)(ks * 16 + n) * 64 + l) * 8);
      acc[n8] = __builtin_amdgcn_mfma_f32_16x16x32_bf16(a, bfr[ks], acc[n8], 0, 0, 0);
    }

  if (rowok) {
#pragma unroll
    for (int n8 = 0; n8 < 8; ++n8) {
      const int c0 = (nh * 8 + n8) * 16 + lg * 4;
      const float4 bv = *(const float4*)(bias + c0);
      ushort4 o;
      o.x = f2bf(acc[n8][0] + bv.x); o.y = f2bf(acc[n8][1] + bv.y);
      o.z = f2bf(acc[n8][2] + bv.z); o.w = f2bf(acc[n8][3] + bv.w);
      *(ushort4*)(outb + (size_t)row * 256 + c0) = o;
    }
  }
}

// ---------------------------------------------------------------------------
// CSR build
// ---------------------------------------------------------------------------
__global__ __launch_bounds__(256)
void dst_hist(const int* __restrict__ dst, int* __restrict__ cnt) {
  const int e = blockIdx.x * 256 + threadIdx.x;
  if (e < NE) atomicAdd(&cnt[dst[e]], 1);
}

__global__ __launch_bounds__(1024)
void scan_bsum(const int* __restrict__ cnt, int* __restrict__ bsum, int n) {
  __shared__ int wsum[16];
  const int tid = threadIdx.x;
  const int lane = tid & 63, wid = tid >> 6;
  const int i = blockIdx.x * 1024 + tid;
  int v = (i < n) ? cnt[i] : 0;
#pragma unroll
  for (int off = 32; off >= 1; off >>= 1) v += __shfl_xor(v, off);
  if (lane == 0) wsum[wid] = v;
  __syncthreads();
  if (tid == 0) {
    int s = 0;
#pragma unroll
    for (int k = 0; k < 16; ++k) s += wsum[k];
    bsum[blockIdx.x] = s;
  }
}

__global__ __launch_bounds__(64)
void scan_bsum_scan(int* __restrict__ bsum, int* __restrict__ row_start,
                    int nb, int n) {
  const int lane = threadIdx.x;
  const int v = (lane < nb) ? bsum[lane] : 0;
  int incl = v;
#pragma unroll
  for (int off = 1; off < 64; off <<= 1) {
    const int t = __shfl_up(incl, off);
    if (lane >= off) incl += t;
  }
  if (lane < nb) bsum[lane] = incl - v;
  if (lane == 63) row_start[n] = incl;
}

__global__ __launch_bounds__(1024)
void scan_apply(int* __restrict__ cnt, const int* __restrict__ bsum,
                int* __restrict__ row_start, int n) {
  __shared__ int wsum[16];
  __shared__ int woff[16];
  const int tid = threadIdx.x;
  const int lane = tid & 63, wid = tid >> 6;
  const int i = blockIdx.x * 1024 + tid;
  const int v = (i < n) ? cnt[i] : 0;
  int incl = v;
#pragma unroll
  for (int off = 1; off < 64; off <<= 1) {
    const int t = __shfl_up(incl, off);
    if (lane >= off) incl += t;
  }
  if (lane == 63) wsum[wid] = incl;
  __syncthreads();
  if (wid == 0) {
    const int s = (lane < 16) ? wsum[lane] : 0;
    int si = s;
#pragma unroll
    for (int off = 1; off < 16; off <<= 1) {
      const int t = __shfl_up(si, off);
      if (lane >= off) si += t;
    }
    if (lane < 16) woff[lane] = si - s;
  }
  __syncthreads();
  if (i < n) {
    const int excl = bsum[blockIdx.x] + woff[wid] + incl - v;
    row_start[i] = excl;
    cnt[i] = excl;
  }
}

__global__ __launch_bounds__(256)
void bucket_fill(const int* __restrict__ src, const int* __restrict__ dst,
                 int* __restrict__ cur, int* __restrict__ eid,
                 int* __restrict__ ssrc, int* __restrict__ sdst) {
  const int e = blockIdx.x * 256 + threadIdx.x;
  if (e < NE) {
    const int d = dst[e];
    const int p = atomicAdd(&cur[d], 1);
    eid[p] = e;
    ssrc[p] = src[e];
    sdst[p] = d;
  }
}

// ---------------------------------------------------------------------------
// eab prep: eab[p][c] = bf16(ea[eid[p]][c]).
// ---------------------------------------------------------------------------
__global__ __launch_bounds__(256)
void conv_eab(const float* __restrict__ ea, const int* __restrict__ eid,
              unsigned short* __restrict__ eab) {
  const int g = blockIdx.x * 256 + threadIdx.x;
  const int p = g >> 4, c4 = (g & 15) * 4;
  const int e = eid[p];
  const float4 v = *(const float4*)(ea + (size_t)e * 64 + c4);
  ushort4 o;
  o.x = f2bf(v.x); o.y = f2bf(v.y); o.z = f2bf(v.z); o.w = f2bf(v.w);
  *(ushort4*)(eab + (size_t)p * 64 + c4) = o;
}

// ---------------------------------------------------------------------------
// per-tile epilogue: MFMA (wef frags x edge frags) + lrelu/att dot.
// ---------------------------------------------------------------------------
static __device__ __forceinline__ float edge_epilogue(
    const unsigned short* __restrict__ xlp,
    const unsigned short* __restrict__ xrp,
    const float* __restrict__ attp,
    const unsigned short* __restrict__ wef,
    bf16x8 f0, bf16x8 f1, int l) {
  float ph = 0.f;
#pragma unroll
  for (int nn = 0; nn < 8; ++nn) {
    const bf16x8 w00 = *(const bf16x8*)(wef + ((size_t)(0  + 2 * nn)     * 64 + l) * 8);
    const bf16x8 w01 = *(const bf16x8*)(wef + ((size_t)(16 + 2 * nn)     * 64 + l) * 8);
    const bf16x8 w10 = *(const bf16x8*)(wef + ((size_t)(0  + 2 * nn + 1) * 64 + l) * 8);
    const bf16x8 w11 = *(const bf16x8*)(wef + ((size_t)(16 + 2 * nn + 1) * 64 + l) * 8);

    f32x4 a0 = (f32x4){0.f,0.f,0.f,0.f}, a1 = (f32x4){0.f,0.f,0.f,0.f};
    a0 = __builtin_amdgcn_mfma_f32_16x16x32_bf16(w00, f0, a0, 0, 0, 0);
    a0 = __builtin_amdgcn_mfma_f32_16x16x32_bf16(w01, f1, a0, 0, 0, 0);
    a1 = __builtin_amdgcn_mfma_f32_16x16x32_bf16(w10, f0, a1, 0, 0, 0);
    a1 = __builtin_amdgcn_mfma_f32_16x16x32_bf16(w11, f1, a1, 0, 0, 0);

    const int c0 = nn * 8;
    const uint4 xu = *(const uint4*)(xlp + c0);
    const uint4 ru = *(const uint4*)(xrp + c0);
    const float4 at0 = *(const float4*)(attp + c0);
    const float4 at1 = *(const float4*)(attp + c0 + 4);
    float v;
    v = a0[0] + bflo(xu.x) + bflo(ru.x); v = LRELU(v); ph += v * at0.x;
    v = a0[1] + bfhi(xu.x) + bfhi(ru.x); v = LRELU(v); ph += v * at0.y;
    v = a0[2] + bflo(xu.y) + bflo(ru.y); v = LRELU(v); ph += v * at0.z;
    v = a0[3] + bfhi(xu.y) + bfhi(ru.y); v = LRELU(v); ph += v * at0.w;
    v = a1[0] + bflo(xu.z) + bflo(ru.z); v = LRELU(v); ph += v * at1.x;
    v = a1[1] + bfhi(xu.z) + bfhi(ru.z); v = LRELU(v); ph += v * at1.y;
    v = a1[2] + bflo(xu.w) + bflo(ru.w); v = LRELU(v); ph += v * at1.z;
    v = a1[3] + bfhi(xu.w) + bfhi(ru.w); v = LRELU(v); ph += v * at1.w;
  }
  return ph;
}

// ---------------------------------------------------------------------------
// Edge kernel, T14 2-tile pipeline (R16 version, kept).
// ---------------------------------------------------------------------------
template <int EAB>
__global__ __launch_bounds__(128)
void edge_logits_swap(const float* __restrict__ ea,
                      const unsigned short* __restrict__ eab,
                      const unsigned short* __restrict__ wef,  // [2][16][64][8]
                      const unsigned short* __restrict__ xlb,
                      const unsigned short* __restrict__ xrb,
                      const float* __restrict__ att,
                      const int* __restrict__ eid,
                      const int* __restrict__ ssrc, const int* __restrict__ sdst,
                      float* __restrict__ elog) {
  __shared__ unsigned short sxl[2][16 * 264];

  const int tid = threadIdx.x;
  const int w = tid >> 6, l = tid & 63;
  const int lid = l & 15, lg = l >> 4;
  const int base = (blockIdx.x * 2 + w) * 32;
  const int pA = base + lid;
  const int pB = base + 16 + lid;

  unsigned short* myxl = sxl[w];
  const int srow_r = l >> 5;
  const int unit   = l & 31;

  bf16x8 fA0, fA1;
  if (EAB) {
    fA0 = *(const bf16x8*)(eab + (size_t)pA * 64 + lg * 8);
    fA1 = *(const bf16x8*)(eab + (size_t)pA * 64 + 32 + lg * 8);
  } else {
    const int e = eid[pA];
    const float* ap = ea + (size_t)e * 64 + lg * 8;
    const float4 v00 = *(const float4*)(ap);
    const float4 v01 = *(const float4*)(ap + 4);
    const float4 v10 = *(const float4*)(ap + 32);
    const float4 v11 = *(const float4*)(ap + 36);
    fA0[0]=f2bf(v00.x); fA0[1]=f2bf(v00.y); fA0[2]=f2bf(v00.z); fA0[3]=f2bf(v00.w);
    fA0[4]=f2bf(v01.x); fA0[5]=f2bf(v01.y); fA0[6]=f2bf(v01.z); fA0[7]=f2bf(v01.w);
    fA1[0]=f2bf(v10.x); fA1[1]=f2bf(v10.y); fA1[2]=f2bf(v10.z); fA1[3]=f2bf(v10.w);
    fA1[4]=f2bf(v11.x); fA1[5]=f2bf(v11.y); fA1[6]=f2bf(v11.z); fA1[7]=f2bf(v11.w);
  }
  const int dA = sdst[pA];

  uint4 gA[8];
#pragma unroll
  for (int i = 0; i < 8; ++i) {
    const int row = i * 2 + srow_r;
    const int srow = ssrc[base + row];
    gA[i] = *(const uint4*)(xlb + (size_t)srow * 256 + unit * 8);
  }

  bf16x8 fB0, fB1;
  if (EAB) {
    fB0 = *(const bf16x8*)(eab + (size_t)pB * 64 + lg * 8);
    fB1 = *(const bf16x8*)(eab + (size_t)pB * 64 + 32 + lg * 8);
  } else {
    const int e = eid[pB];
    const float* ap = ea + (size_t)e * 64 + lg * 8;
    const float4 v00 = *(const float4*)(ap);
    const float4 v01 = *(const float4*)(ap + 4);
    const float4 v10 = *(const float4*)(ap + 32);
    const float4 v11 = *(const float4*)(ap + 36);
    fB0[0]=f2bf(v00.x); fB0[1]=f2bf(v00.y); fB0[2]=f2bf(v00.z); fB0[3]=f2bf(v00.w);
    fB0[4]=f2bf(v01.x); fB0[5]=f2bf(v01.y); fB0[6]=f2bf(v01.z); fB0[7]=f2bf(v01.w);
    fB1[0]=f2bf(v10.x); fB1[1]=f2bf(v10.y); fB1[2]=f2bf(v10.z); fB1[3]=f2bf(v10.w);
    fB1[4]=f2bf(v11.x); fB1[5]=f2bf(v11.y); fB1[6]=f2bf(v11.z); fB1[7]=f2bf(v11.w);
  }
  const int dB = sdst[pB];

  uint4 gB[8];
#pragma unroll
  for (int i = 0; i < 8; ++i) {
    const int row = i * 2 + srow_r;
    const int srow = ssrc[base + 16 + row];
    gB[i] = *(const uint4*)(xlb + (size_t)srow * 256 + unit * 8);
  }

#pragma unroll
  for (int i = 0; i < 8; ++i) {
    const int row = i * 2 + srow_r;
    *(uint4*)&myxl[row * 264 + unit * 8] = gA[i];
  }
  const float phA = edge_epilogue(myxl + lid * 264 + lg * 64,
                                  xrb + (size_t)dA * 256 + lg * 64,
                                  att + lg * 64, wef, fA0, fA1, l);
  elog[(size_t)pA * 4 + lg] = expf(phA);

#pragma unroll
  for (int i = 0; i < 8; ++i) {
    const int row = i * 2 + srow_r;
    *(uint4*)&myxl[row * 264 + unit * 8] = gB[i];
  }
  const float phB = edge_epilogue(myxl + lid * 264 + lg * 64,
                                  xrb + (size_t)dB * 256 + lg * 64,
                                  att + lg * 64, wef, fB0, fB1, l);
  elog[(size_t)pB * 4 + lg] = expf(phB);
}

// ---------------------------------------------------------------------------
// Aggregation (R13 pattern). FINAL=1 -> fp32 d_out; FINAL=0 -> bf16 h1b.
// ---------------------------------------------------------------------------
template <int FINAL>
__global__ __launch_bounds__(256)
void aggregate(const unsigned short* __restrict__ xlb,
               const float* __restrict__ elog,
               const int* __restrict__ ssrc, const int* __restrict__ row_start,
               const float* __restrict__ bias, float* __restrict__ outf,
               unsigned short* __restrict__ outb) {
  const int wid  = threadIdx.x >> 6;
  const int lane = threadIdx.x & 63;
  const int d    = blockIdx.x * 4 + wid;
  const int h = lane >> 4;
  const int c = lane * 4;
  float ax = 0.f, ay = 0.f, az = 0.f, aw = 0.f;
  float dtot = 0.f;
  const int beg = row_start[d], end = row_start[d + 1];
  int p = beg;
  for (; p + 4 <= end; p += 4) {
    const float e0 = elog[(size_t)(p + 0) * 4 + h];
    const float e1 = elog[(size_t)(p + 1) * 4 + h];
    const float e2 = elog[(size_t)(p + 2) * 4 + h];
    const float e3 = elog[(size_t)(p + 3) * 4 + h];
    const int s0 = ssrc[p + 0], s1 = ssrc[p + 1];
    const int s2 = ssrc[p + 2], s3 = ssrc[p + 3];
    const uint2 x0 = *(const uint2*)(xlb + (size_t)s0 * 256 + c);
    const uint2 x1 = *(const uint2*)(xlb + (size_t)s1 * 256 + c);
    const uint2 x2 = *(const uint2*)(xlb + (size_t)s2 * 256 + c);
    const uint2 x3 = *(const uint2*)(xlb + (size_t)s3 * 256 + c);
    ax += e0*bflo(x0.x) + e1*bflo(x1.x) + e2*bflo(x2.x) + e3*bflo(x3.x);
    ay += e0*bfhi(x0.x) + e1*bfhi(x1.x) + e2*bfhi(x2.x) + e3*bfhi(x3.x);
    az += e0*bflo(x0.y) + e1*bflo(x1.y) + e2*bflo(x2.y) + e3*bflo(x3.y);
    aw += e0*bfhi(x0.y) + e1*bfhi(x1.y) + e2*bfhi(x2.y) + e3*bfhi(x3.y);
    dtot += e0 + e1 + e2 + e3;
  }
  for (; p < end; ++p) {
    const float ev = elog[(size_t)p * 4 + h];
    const int s = ssrc[p];
    const uint2 xv = *(const uint2*)(xlb + (size_t)s * 256 + c);
    ax += ev * bflo(xv.x); ay += ev * bfhi(xv.x);
    az += ev * bflo(xv.y); aw += ev * bfhi(xv.y);
    dtot += ev;
  }
  const float inv = 1.f / (dtot + 1e-16f);
  const float4 bv = *(const float4*)(bias + c);
  float4 o;
  o.x = bv.x + ax * inv; o.y = bv.y + ay * inv;
  o.z = bv.z + az * inv; o.w = bv.w + aw * inv;
  if (FINAL) {
    *(float4*)(outf + (size_t)d * 256 + c) = o;
  } else {
    ushort4 ob;
    ob.x = f2bf(o.x); ob.y = f2bf(o.y); ob.z = f2bf(o.z); ob.w = f2bf(o.w);
    *(ushort4*)(outb + (size_t)d * 256 + c) = ob;
  }
}

extern "C" void kernel_launch(void* const* d_in, const int* in_sizes, int n_in,
                              void* d_out, int out_size, void* d_ws, size_t ws_size,
                              hipStream_t stream) {
  const float* x    = (const float*)d_in[0];
  const int*   ei   = (const int*)d_in[1];
  const float* ea   = (const float*)d_in[2];
  const float* Wl1  = (const float*)d_in[3];
  const float* bl1  = (const float*)d_in[4];
  const float* Wr1  = (const float*)d_in[5];
  const float* br1  = (const float*)d_in[6];
  const float* We1  = (const float*)d_in[7];
  const float* att1 = (const float*)d_in[8];
  const float* bias1= (const float*)d_in[9];
  const float* Wl2  = (const float*)d_in[10];
  const float* bl2  = (const float*)d_in[11];
  const float* Wr2  = (const float*)d_in[12];
  const float* br2  = (const float*)d_in[13];
  const float* We2  = (const float*)d_in[14];
  const float* att2 = (const float*)d_in[15];
  const float* bias2= (const float*)d_in[16];

  float* out = (float*)d_out;
  float* ws  = (float*)d_ws;

  float* elog = ws;                                    // NE*4 f32
  unsigned short* xlb  = (unsigned short*)(elog + (size_t)NE * 4); // NN*256
  unsigned short* xrb  = xlb + (size_t)NN * 256;       // NN*256
  unsigned short* h1b  = xrb + (size_t)NN * 256;       // NN*256
  unsigned short* wef1 = h1b + (size_t)NN * 256;       // 16384
  unsigned short* wef2 = wef1 + 16384;                 // 16384
  unsigned short* wlf1 = wef2 + 16384;                 // 32768
  unsigned short* wrf1 = wlf1 + 32768;                 // 32768
  unsigned short* wlf2 = wrf1 + 32768;                 // 65536
  unsigned short* wrf2 = wlf2 + 65536;                 // 65536
  int* cur       = (int*)(wrf2 + 65536);               // NN
  int* row_start = cur + NN;                           // NN+1
  int* bsum      = row_start + NN + 1;                 // 64
  int* eid       = bsum + 64;                          // NE
  int* ssrc      = eid + NE;                           // NE
  int* sdst      = ssrc + NE;                          // NE
  unsigned short* eab = (unsigned short*)(sdst + NE);  // NE*64 bf16 (optional)
  const size_t need_eab =
      ((char*)(eab + (size_t)NE * 64)) - (char*)d_ws;
  const bool use_eab = ws_size >= need_eab;

  const int* src = ei;
  const int* dst = ei + NE;

  const int ggrid = (NN + 63) / 64;      // 782
  const int egrid = NE / 64;             // 12500 (2 waves x 32 / block)
  const int epb   = (NE + 255) / 256;
  const int agrid = NN / 4;              // 12500
  const int nb    = (NN + 1023) / 1024;  // 49

  // ---- prep: CSR + bf16 weight tables (+ eab) ----
  hipMemsetAsync(cur, 0, NN * sizeof(int), stream);
  conv_all<<<dim3(256, 6), 256, 0, stream>>>(We1, wef1, We2, wef2,
                                             Wl1, wlf1, Wr1, wrf1,
                                             Wl2, wlf2, Wr2, wrf2);
  dst_hist<<<epb, 256, 0, stream>>>(dst, cur);
  scan_bsum<<<nb, 1024, 0, stream>>>(cur, bsum, NN);
  scan_bsum_scan<<<1, 64, 0, stream>>>(bsum, row_start, nb, NN);
  scan_apply<<<nb, 1024, 0, stream>>>(cur, bsum, row_start, NN);
  bucket_fill<<<epb, 256, 0, stream>>>(src, dst, cur, eid, ssrc, sdst);
  if (use_eab)
    conv_eab<<<NE * 16 / 256, 256, 0, stream>>>(ea, eid, eab);

  // ---- layer 1 ----
  gemm_mfma4<4, 0><<<dim3(ggrid, 4), 256, 0, stream>>>(x, wlf1, bl1, xlb,
                                                       wrf1, br1, xrb);
  if (use_eab)
    edge_logits_swap<1><<<egrid, 128, 0, stream>>>(ea, eab, wef1, xlb, xrb,
                                                   att1, eid, ssrc, sdst, elog);
  else
    edge_logits_swap<0><<<egrid, 128, 0, stream>>>(ea, eab, wef1, xlb, xrb,
                                                   att1, eid, ssrc, sdst, elog);
  aggregate<0><<<agrid, 256, 0, stream>>>(xlb, elog, ssrc, row_start, bias1,
                                          nullptr, h1b);

  // ---- layer 2 ----
  gemm_mfma4<8, 1><<<dim3(ggrid, 4), 256, 0, stream>>>(h1b, wlf2, bl2, xlb,
                                                       wrf2, br2, xrb);
  if (use_eab)
    edge_logits_swap<1><<<egrid, 128, 0, stream>>>(ea, eab, wef2, xlb, xrb,
                                                   att2, eid, ssrc, sdst, elog);
  else
    edge_logits_swap<0><<<egrid, 128, 0, stream>>>(ea, eab, wef2, xlb, xrb,
                                                   att2, eid, ssrc, sdst, elog);
  aggregate<1><<<agrid, 256, 0, stream>>>(xlb, elog, ssrc, row_start, bias2,
                                          out, nullptr);
}